// Round 1
// baseline (924.314 us; speedup 1.0000x reference)
//
#include <hip/hip_runtime.h>
#include <math.h>

#define NQ 4096
#define CC 256

// ---------------------------------------------------------------- transpose
// S [B, C, Nq] -> Sseq [B*Nq, C]
__global__ __launch_bounds__(256)
void transpose_k(const float* __restrict__ S, float* __restrict__ Sseq) {
  __shared__ float t[32][33];
  int q0 = blockIdx.x * 32, c0 = blockIdx.y * 32, b = blockIdx.z;
  int tx = threadIdx.x, ty = threadIdx.y;
  const float* Sb = S + (size_t)b * CC * NQ;
  for (int i = ty; i < 32; i += 8)
    t[i][tx] = Sb[(size_t)(c0 + i) * NQ + q0 + tx];
  __syncthreads();
  float* Ob = Sseq + (size_t)b * NQ * CC;
  for (int i = ty; i < 32; i += 8)
    Ob[(size_t)(q0 + i) * CC + c0 + tx] = t[tx][i];
}

// ---------------------------------------------------------------- GEMM
// out[m,n] = sum_k X(m,k) * W[n*K+k] + bias[n]
// TRANSX: X layout [b][K][Mb] (channel-major feature maps), m = b*Mb + p
// EPI: 0 = plain store, 1 = exact GELU, 2 = +Zres residual, store transposed
//      to outT[(b*CC+n)*NQ + q]
template<bool TRANSX, int EPI>
__global__ __launch_bounds__(256)
void gemm_k(const float* __restrict__ X, const float* __restrict__ W,
            const float* __restrict__ bias, float* __restrict__ out,
            int Mb, int K, int N,
            const float* __restrict__ Zres, float* __restrict__ outT)
{
  __shared__ float Xs[16][68];
  __shared__ float Ws[16][68];
  int tid = threadIdx.x;
  int n0 = blockIdx.x * 64;
  int m0 = blockIdx.y * 64;
  int b = m0 / Mb;        // only meaningful for TRANSX (tiles never cross batch)
  int p0 = m0 - b * Mb;
  float acc[4][4] = {};
  int tx = tid & 15, ty = tid >> 4;

  for (int k0 = 0; k0 < K; k0 += 16) {
    if (TRANSX) {
      int ml = tid & 63;
      #pragma unroll
      for (int kk = tid >> 6; kk < 16; kk += 4)
        Xs[kk][ml] = X[(size_t)b * K * Mb + (size_t)(k0 + kk) * Mb + p0 + ml];
    } else {
      int kk = tid & 15;
      #pragma unroll
      for (int ml = tid >> 4; ml < 64; ml += 16)
        Xs[kk][ml] = X[(size_t)(m0 + ml) * K + k0 + kk];
    }
    {
      int kk = tid & 15;
      #pragma unroll
      for (int nl = tid >> 4; nl < 64; nl += 16) {
        int n = n0 + nl;
        Ws[kk][nl] = (n < N) ? W[(size_t)n * K + k0 + kk] : 0.f;
      }
    }
    __syncthreads();
    #pragma unroll
    for (int k = 0; k < 16; k++) {
      float a[4], bb[4];
      #pragma unroll
      for (int i = 0; i < 4; i++) a[i] = Xs[k][ty * 4 + i];
      #pragma unroll
      for (int j = 0; j < 4; j++) bb[j] = Ws[k][tx * 4 + j];
      #pragma unroll
      for (int i = 0; i < 4; i++)
        #pragma unroll
        for (int j = 0; j < 4; j++)
          acc[i][j] += a[i] * bb[j];
    }
    __syncthreads();
  }

  #pragma unroll
  for (int i = 0; i < 4; i++) {
    int m = m0 + ty * 4 + i;
    #pragma unroll
    for (int j = 0; j < 4; j++) {
      int n = n0 + tx * 4 + j;
      if (n < N) {
        float v = acc[i][j] + bias[n];
        if (EPI == 1) v = 0.5f * v * (1.f + erff(v * 0.70710678118654752f));
        if (EPI == 2) {
          v += Zres[(size_t)m * CC + n];
          int bb2 = m >> 12, q = m & (NQ - 1);
          outT[((size_t)bb2 * CC + n) * NQ + q] = v;
        } else {
          out[(size_t)m * N + n] = v;
        }
      }
    }
  }
}

// ---------------------------------------------------------------- LayerNorm
// one block per row of 256; optional residual R; in-place safe
__global__ __launch_bounds__(256)
void ln_k(const float* __restrict__ X, const float* __restrict__ R,
          const float* __restrict__ g, const float* __restrict__ be,
          float* __restrict__ out)
{
  int row = blockIdx.x, c = threadIdx.x;
  float x = X[(size_t)row * CC + c];
  if (R) x += R[(size_t)row * CC + c];
  float s1 = x, s2 = x * x;
  #pragma unroll
  for (int o = 32; o > 0; o >>= 1) {
    s1 += __shfl_down(s1, o);
    s2 += __shfl_down(s2, o);
  }
  __shared__ float p1[4], p2[4];
  __shared__ float mu_s, rs_s;
  int w = c >> 6;
  if ((c & 63) == 0) { p1[w] = s1; p2[w] = s2; }
  __syncthreads();
  if (c == 0) {
    float a = p1[0] + p1[1] + p1[2] + p1[3];
    float b2 = p2[0] + p2[1] + p2[2] + p2[3];
    float mu = a * (1.f / 256.f);
    float var = b2 * (1.f / 256.f) - mu * mu;
    mu_s = mu;
    rs_s = rsqrtf(var + 1e-5f);
  }
  __syncthreads();
  out[(size_t)row * CC + c] = (x - mu_s) * rs_s * g[c] + be[c];
}

// ---------------------------------------------------------------- sampling
// block per (b,n): wave h handles head h; lane handles 4 channels (float4)
__global__ __launch_bounds__(256)
void sample_k(const float* __restrict__ offb, const float* __restrict__ wgtb,
              const float* __restrict__ sim,
              const float* __restrict__ V0, const float* __restrict__ V1,
              const float* __restrict__ V2, float* __restrict__ acc)
{
  int bn = blockIdx.x;
  int b = bn >> 12, n = bn & (NQ - 1);
  int tid = threadIdx.x;
  int head = tid >> 6, lane = tid & 63;

  __shared__ float s_fx[48], s_fy[48], s_w[48];
  __shared__ int s_xi[48], s_yi[48];

  if (tid < 48) {
    int hh = tid / 12, pt = tid % 12, l = pt >> 2, mm = pt & 3;
    int oidx = ((hh * 3 + l) * 4 + mm);
    float offx = offb[(size_t)bn * 96 + oidx * 2 + 0];
    float offy = offb[(size_t)bn * 96 + oidx * 2 + 1];
    float refx = ((n & 63) + 0.5f) * (1.f / 64.f);
    float refy = ((n >> 6) + 0.5f) * (1.f / 64.f);
    float gx = tanhf((refx + offx) * 2.f - 1.f);
    float gy = tanhf((refy + offy) * 2.f - 1.f);
    gx = fminf(1.f, fmaxf(-1.f, gx));
    gy = fminf(1.f, fmaxf(-1.f, gy));
    int Wl = 64 >> l;
    float x = (gx + 1.f) * 0.5f * (float)(Wl - 1);
    float y = (gy + 1.f) * 0.5f * (float)(Wl - 1);
    float x0 = floorf(x), y0 = floorf(y);
    s_xi[tid] = (int)x0;
    s_yi[tid] = (int)y0;
    s_fx[tid] = x - x0;
    s_fy[tid] = y - y0;
    s_w[tid] = wgtb[(size_t)bn * 48 + oidx] * (sim[bn] + 0.001f);
  }
  __syncthreads();
  if (tid < 4) {
    float mx = -1e30f;
    #pragma unroll
    for (int i = 0; i < 12; i++) mx = fmaxf(mx, s_w[tid * 12 + i]);
    float e[12], ssum = 0.f;
    #pragma unroll
    for (int i = 0; i < 12; i++) { e[i] = expf(s_w[tid * 12 + i] - mx); ssum += e[i]; }
    float inv = 1.f / ssum;
    #pragma unroll
    for (int i = 0; i < 12; i++) s_w[tid * 12 + i] = e[i] * inv;
  }
  __syncthreads();

  float4 a = make_float4(0.f, 0.f, 0.f, 0.f);
  #pragma unroll
  for (int pt = 0; pt < 12; pt++) {
    int s = head * 12 + pt;
    int l = pt >> 2;
    const float* V = (l == 0) ? V0 : (l == 1) ? V1 : V2;
    int Wl = 64 >> l;
    int Pl = Wl * Wl;
    int xi = s_xi[s], yi = s_yi[s];
    float fx = s_fx[s], fy = s_fy[s], w = s_w[s];
    const float* base = V + (size_t)b * Pl * CC;
    #pragma unroll
    for (int dy = 0; dy < 2; dy++) {
      #pragma unroll
      for (int dx = 0; dx < 2; dx++) {
        int X_ = xi + dx, Y_ = yi + dy;
        if (X_ >= 0 && X_ < Wl && Y_ >= 0 && Y_ < Wl) {
          float tw = w * (dx ? fx : 1.f - fx) * (dy ? fy : 1.f - fy);
          const float4 v = *(const float4*)(base + ((size_t)(Y_ * Wl + X_)) * CC + lane * 4);
          a.x += tw * v.x; a.y += tw * v.y; a.z += tw * v.z; a.w += tw * v.w;
        }
      }
    }
  }
  *(float4*)(acc + (size_t)bn * 1024 + head * CC + lane * 4) = a;
}

// ---------------------------------------------------------------- launch
extern "C" void kernel_launch(void* const* d_in, const int* in_sizes, int n_in,
                              void* d_out, int out_size, void* d_ws, size_t ws_size,
                              hipStream_t stream)
{
  const float* S     = (const float*)d_in[0];
  const float* f0    = (const float*)d_in[1];
  const float* f1    = (const float*)d_in[2];
  const float* f2    = (const float*)d_in[3];
  const float* sim   = (const float*)d_in[4];
  const float* vw0   = (const float*)d_in[5];
  const float* vb0   = (const float*)d_in[6];
  const float* vw1   = (const float*)d_in[7];
  const float* vb1   = (const float*)d_in[8];
  const float* vw2   = (const float*)d_in[9];
  const float* vb2   = (const float*)d_in[10];
  const float* q_w   = (const float*)d_in[11];
  const float* q_b   = (const float*)d_in[12];
  const float* off_w = (const float*)d_in[13];
  const float* off_b = (const float*)d_in[14];
  const float* wgt_w = (const float*)d_in[15];
  const float* wgt_b = (const float*)d_in[16];
  const float* out_w = (const float*)d_in[17];
  const float* out_b = (const float*)d_in[18];
  const float* lnq_g = (const float*)d_in[19];
  const float* lnq_b = (const float*)d_in[20];
  const float* lno_g = (const float*)d_in[21];
  const float* lno_b = (const float*)d_in[22];
  const float* fc1_w = (const float*)d_in[23];
  const float* fc1_b = (const float*)d_in[24];
  const float* fc2_w = (const float*)d_in[25];
  const float* fc2_b = (const float*)d_in[26];

  float* ws = (float*)d_ws;
  float* Sseq = ws;                 // 2,097,152
  float* Q    = ws + 2097152;       // 2,097,152  (reused as Yraw)
  float* offb = ws + 4194304;       //   786,432
  float* wgtb = ws + 4980736;       //   393,216
  float* V0   = ws + 5373952;       // 2,097,152  (reused as Z)
  float* V1   = ws + 7471104;       //   524,288
  float* V2   = ws + 7995392;       //   131,072
  float* accb = ws + 8126464;       // 8,388,608  (reused as h)
  float* Yraw = Q;
  float* Z    = V0;
  float* hbuf = accb;
  float* outp = (float*)d_out;

  // 1. S -> Sseq
  transpose_k<<<dim3(128, 8, 2), dim3(32, 8), 0, stream>>>(S, Sseq);
  // 2. Qraw = Sseq @ q_w^T + q_b
  gemm_k<false, 0><<<dim3(4, 128), 256, 0, stream>>>(Sseq, q_w, q_b, Q, 8192, 256, 256, nullptr, nullptr);
  // 3. Q = LN(Qraw)
  ln_k<<<8192, 256, 0, stream>>>(Q, nullptr, lnq_g, lnq_b, Q);
  // 4. off = Q @ off_w^T + off_b
  gemm_k<false, 0><<<dim3(2, 128), 256, 0, stream>>>(Q, off_w, off_b, offb, 8192, 256, 96, nullptr, nullptr);
  // 5. wgt = Q @ wgt_w^T + wgt_b
  gemm_k<false, 0><<<dim3(1, 128), 256, 0, stream>>>(Q, wgt_w, wgt_b, wgtb, 8192, 256, 48, nullptr, nullptr);
  // 6-8. V projections (1x1 conv): feature maps are [b][Cin][P] -> TRANSX
  gemm_k<true, 0><<<dim3(4, 128), 256, 0, stream>>>(f0, vw0, vb0, V0, 4096, 256, 256, nullptr, nullptr);
  gemm_k<true, 0><<<dim3(4, 32), 256, 0, stream>>>(f1, vw1, vb1, V1, 1024, 512, 256, nullptr, nullptr);
  gemm_k<true, 0><<<dim3(4, 8), 256, 0, stream>>>(f2, vw2, vb2, V2, 256, 1024, 256, nullptr, nullptr);
  // 9. softmax + deformable sampling -> acc [8192, 1024]
  sample_k<<<8192, 256, 0, stream>>>(offb, wgtb, sim, V0, V1, V2, accb);
  // 10. Yraw = acc @ out_w^T + out_b
  gemm_k<false, 0><<<dim3(4, 128), 256, 0, stream>>>(accb, out_w, out_b, Yraw, 8192, 1024, 256, nullptr, nullptr);
  // 11. Z = LN(Sseq + Yraw)
  ln_k<<<8192, 256, 0, stream>>>(Yraw, Sseq, lno_g, lno_b, Z);
  // 12. h = gelu(Z @ fc1_w^T + fc1_b)
  gemm_k<false, 1><<<dim3(16, 128), 256, 0, stream>>>(Z, fc1_w, fc1_b, hbuf, 8192, 256, 1024, nullptr, nullptr);
  // 13. out = transpose(Z + h @ fc2_w^T + fc2_b)
  gemm_k<false, 2><<<dim3(4, 128), 256, 0, stream>>>(hbuf, fc2_w, fc2_b, nullptr, 8192, 1024, 256, Z, outp);
}

// Round 2
// 371.549 us; speedup vs baseline: 2.4877x; 2.4877x over previous
//
#include <hip/hip_runtime.h>
#include <hip/hip_bf16.h>
#include <math.h>

#define NQ 4096
#define CC 256

typedef __attribute__((ext_vector_type(8))) short bfrag;
typedef __attribute__((ext_vector_type(4))) float ffrag;

__device__ inline unsigned short f2bf(float x) {
  __hip_bfloat16 h = __float2bfloat16(x);
  return *reinterpret_cast<unsigned short*>(&h);
}

__device__ inline void gload16(const void* g, void* l) {
  __builtin_amdgcn_global_load_lds(
      (const __attribute__((address_space(1))) void*)g,
      (__attribute__((address_space(3))) void*)l, 16, 0, 0);
}

// ------------------------------------------------- S transpose (fp32 + bf16)
__global__ __launch_bounds__(256)
void transpose_bf_k(const float* __restrict__ S, float* __restrict__ Sseq,
                    unsigned short* __restrict__ Sbf) {
  __shared__ float t[32][33];
  int q0 = blockIdx.x * 32, c0 = blockIdx.y * 32, b = blockIdx.z;
  int tx = threadIdx.x, ty = threadIdx.y;
  const float* Sb = S + (size_t)b * CC * NQ;
  for (int i = ty; i < 32; i += 8)
    t[i][tx] = Sb[(size_t)(c0 + i) * NQ + q0 + tx];
  __syncthreads();
  size_t ob = (size_t)b * NQ * CC;
  for (int i = ty; i < 32; i += 8) {
    float v = t[tx][i];
    size_t idx = ob + (size_t)(q0 + i) * CC + c0 + tx;
    Sseq[idx] = v;
    Sbf[idx] = f2bf(v);
  }
}

// ------------------------------------------------- feature transpose -> bf16
// F [B][Cin][P] -> X bf16 [B*P][Cin]
__global__ __launch_bounds__(256)
void transpose_feat_k(const float* __restrict__ F, unsigned short* __restrict__ X,
                      int Cin, int P) {
  __shared__ float t[32][33];
  int p0 = blockIdx.x * 32, c0 = blockIdx.y * 32, b = blockIdx.z;
  int tx = threadIdx.x, ty = threadIdx.y;
  const float* Fb = F + (size_t)b * Cin * P;
  for (int i = ty; i < 32; i += 8)
    t[i][tx] = Fb[(size_t)(c0 + i) * P + p0 + tx];
  __syncthreads();
  unsigned short* Xb = X + (size_t)b * P * Cin;
  for (int i = ty; i < 32; i += 8)
    Xb[(size_t)(p0 + i) * Cin + c0 + tx] = f2bf(t[tx][i]);
}

// ------------------------------------------------- weight prep (fp32->bf16)
__global__ __launch_bounds__(256)
void prep_w_k(const float* q_w, const float* off_w, const float* wgt_w,
              const float* vw0, const float* vw1, const float* vw2,
              const float* out_w, const float* fc1_w, const float* fc2_w,
              const float* off_b, const float* wgt_b,
              unsigned short* q_wb, unsigned short* owb, unsigned short* vw0b,
              unsigned short* vw1b, unsigned short* vw2b, unsigned short* out_wb,
              unsigned short* fc1_wb, unsigned short* fc2_wb, float* bias144) {
  int seg = blockIdx.y;
  int idx = blockIdx.x * 256 + threadIdx.x;
  const float* src = nullptr; unsigned short* dst = nullptr; int len = 0;
  switch (seg) {
    case 0: src = q_w;   dst = q_wb;   len = 65536;  break;
    case 1: dst = owb; len = 65536; break; // special
    case 2: src = vw0;   dst = vw0b;  len = 65536;  break;
    case 3: src = vw1;   dst = vw1b;  len = 131072; break;
    case 4: src = vw2;   dst = vw2b;  len = 262144; break;
    case 5: src = out_w; dst = out_wb; len = 262144; break;
    case 6: src = fc1_w; dst = fc1_wb; len = 262144; break;
    case 7: src = fc2_w; dst = fc2_wb; len = 262144; break;
  }
  if (idx >= len) return;
  if (seg == 1) {
    float v = (idx < 24576) ? off_w[idx] : (idx < 36864 ? wgt_w[idx - 24576] : 0.f);
    dst[idx] = f2bf(v);
    if (idx < 96) bias144[idx] = off_b[idx];
    else if (idx < 144) bias144[idx] = wgt_b[idx - 96];
  } else {
    dst[idx] = f2bf(src[idx]);
  }
}

// ------------------------------------------------- MFMA GEMM 128x128, BK=32
// out[m,n] = sum_k A_bf16[m,k] * B_bf16[n,k] + bias[n]
// EPI 0: fp32 store (ld=ldo)   EPI 1: exact GELU -> bf16 store
// EPI 2: + Zres[m,256], store transposed fp32 to outT[(b*256+n)*4096+q]
template<int EPI>
__global__ __launch_bounds__(256)
void mgemm_k(const unsigned short* __restrict__ A,
             const unsigned short* __restrict__ B,
             const float* __restrict__ bias,
             float* __restrict__ outf, unsigned short* __restrict__ outb,
             int N, int K, int ldo,
             const float* __restrict__ Zres, float* __restrict__ outT) {
  __shared__ __attribute__((aligned(16))) unsigned short As[4096];
  __shared__ __attribute__((aligned(16))) unsigned short Bs[4096];
  int tid = threadIdx.x;
  int wave = tid >> 6, lane = tid & 63;
  int quad = lane >> 4, l16 = lane & 15;
  int wm = wave >> 1, wn = wave & 1;
  int m0 = blockIdx.y * 128, n0 = blockIdx.x * 128;

  ffrag acc[4][4];
  #pragma unroll
  for (int i = 0; i < 4; i++)
    #pragma unroll
    for (int j = 0; j < 4; j++)
      acc[i][j] = (ffrag)0.f;

  // staging: 512 chunks of 16B per 128x32 tile; wave w covers chunks
  // [w*64, w*64+64) and [256+w*64, 256+w*64+64); chunk c -> row c>>2, kc c&3
  int row = wave * 16 + (lane >> 2);
  int kc8 = (lane & 3) * 8;
  const unsigned short* Ag  = A + (size_t)(m0 + row) * K + kc8;
  const unsigned short* Ag2 = Ag + (size_t)64 * K;
  const unsigned short* Bg  = B + (size_t)(n0 + row) * K + kc8;
  const unsigned short* Bg2 = Bg + (size_t)64 * K;
  unsigned short* AsW  = As + wave * 512;
  unsigned short* AsW2 = As + 2048 + wave * 512;
  unsigned short* BsW  = Bs + wave * 512;
  unsigned short* BsW2 = Bs + 2048 + wave * 512;

  for (int k0 = 0; k0 < K; k0 += 32) {
    __syncthreads();
    gload16(Ag, AsW);  gload16(Ag2, AsW2);
    gload16(Bg, BsW);  gload16(Bg2, BsW2);
    Ag += 32; Ag2 += 32; Bg += 32; Bg2 += 32;
    __syncthreads();
    bfrag af[4], bfv[4];
    #pragma unroll
    for (int i = 0; i < 4; i++)
      af[i] = *(const bfrag*)(As + ((wm * 64 + i * 16 + l16) << 5) + (quad << 3));
    #pragma unroll
    for (int i = 0; i < 4; i++)
      bfv[i] = *(const bfrag*)(Bs + ((wn * 64 + i * 16 + l16) << 5) + (quad << 3));
    #pragma unroll
    for (int mi = 0; mi < 4; mi++)
      #pragma unroll
      for (int ni = 0; ni < 4; ni++)
        acc[mi][ni] = __builtin_amdgcn_mfma_f32_16x16x32_bf16(
            af[mi], bfv[ni], acc[mi][ni], 0, 0, 0);
  }

  int mb = m0 + wm * 64, nb = n0 + wn * 64;
  #pragma unroll
  for (int mi = 0; mi < 4; mi++) {
    #pragma unroll
    for (int ni = 0; ni < 4; ni++) {
      int n = nb + ni * 16 + l16;
      bool nok = (n < N);
      float bv = nok ? bias[n] : 0.f;
      #pragma unroll
      for (int r = 0; r < 4; r++) {
        int m = mb + mi * 16 + quad * 4 + r;
        float v = acc[mi][ni][r] + bv;
        if (EPI == 0) {
          if (nok) outf[(size_t)m * ldo + n] = v;
        } else if (EPI == 1) {
          v = 0.5f * v * (1.f + erff(v * 0.70710678118654752f));
          if (nok) outb[(size_t)m * ldo + n] = f2bf(v);
        } else {
          v += Zres[(size_t)m * CC + n];
          outT[((size_t)(m >> 12) * CC + n) * NQ + (m & (NQ - 1))] = v;
        }
      }
    }
  }
}

// ------------------------------------------------- LayerNorm (dual output)
__global__ __launch_bounds__(256)
void ln_k(const float* __restrict__ X, const float* __restrict__ R,
          const float* __restrict__ g, const float* __restrict__ be,
          float* __restrict__ outf, unsigned short* __restrict__ outb) {
  int rowi = blockIdx.x, c = threadIdx.x;
  float x = X[(size_t)rowi * CC + c];
  if (R) x += R[(size_t)rowi * CC + c];
  float s1 = x, s2 = x * x;
  #pragma unroll
  for (int o = 32; o > 0; o >>= 1) {
    s1 += __shfl_down(s1, o);
    s2 += __shfl_down(s2, o);
  }
  __shared__ float p1[4], p2[4];
  __shared__ float mu_s, rs_s;
  int w = c >> 6;
  if ((c & 63) == 0) { p1[w] = s1; p2[w] = s2; }
  __syncthreads();
  if (c == 0) {
    float a = p1[0] + p1[1] + p1[2] + p1[3];
    float b2 = p2[0] + p2[1] + p2[2] + p2[3];
    float mu = a * (1.f / 256.f);
    float var = b2 * (1.f / 256.f) - mu * mu;
    mu_s = mu;
    rs_s = rsqrtf(var + 1e-5f);
  }
  __syncthreads();
  float y = (x - mu_s) * rs_s * g[c] + be[c];
  if (outf) outf[(size_t)rowi * CC + c] = y;
  if (outb) outb[(size_t)rowi * CC + c] = f2bf(y);
}

// ------------------------------------------------- sampling -> bf16 acc
__global__ __launch_bounds__(256)
void sample_k(const float* __restrict__ ow, const float* __restrict__ sim,
              const float* __restrict__ V0, const float* __restrict__ V1,
              const float* __restrict__ V2, unsigned short* __restrict__ acc) {
  int bn = blockIdx.x;
  int b = bn >> 12, n = bn & (NQ - 1);
  int tid = threadIdx.x;
  int head = tid >> 6, lane = tid & 63;

  __shared__ float s_fx[48], s_fy[48], s_w[48];
  __shared__ int s_xi[48], s_yi[48];

  if (tid < 48) {
    int hh = tid / 12, pt = tid % 12, l = pt >> 2, mm = pt & 3;
    int oidx = ((hh * 3 + l) * 4 + mm);
    float offx = ow[(size_t)bn * 144 + oidx * 2 + 0];
    float offy = ow[(size_t)bn * 144 + oidx * 2 + 1];
    float refx = ((n & 63) + 0.5f) * (1.f / 64.f);
    float refy = ((n >> 6) + 0.5f) * (1.f / 64.f);
    float gx = tanhf((refx + offx) * 2.f - 1.f);
    float gy = tanhf((refy + offy) * 2.f - 1.f);
    gx = fminf(1.f, fmaxf(-1.f, gx));
    gy = fminf(1.f, fmaxf(-1.f, gy));
    int Wl = 64 >> l;
    float x = (gx + 1.f) * 0.5f * (float)(Wl - 1);
    float y = (gy + 1.f) * 0.5f * (float)(Wl - 1);
    float x0 = floorf(x), y0 = floorf(y);
    s_xi[tid] = (int)x0;
    s_yi[tid] = (int)y0;
    s_fx[tid] = x - x0;
    s_fy[tid] = y - y0;
    s_w[tid] = ow[(size_t)bn * 144 + 96 + oidx] * (sim[bn] + 0.001f);
  }
  __syncthreads();
  if (tid < 4) {
    float mx = -1e30f;
    #pragma unroll
    for (int i = 0; i < 12; i++) mx = fmaxf(mx, s_w[tid * 12 + i]);
    float e[12], ssum = 0.f;
    #pragma unroll
    for (int i = 0; i < 12; i++) { e[i] = expf(s_w[tid * 12 + i] - mx); ssum += e[i]; }
    float inv = 1.f / ssum;
    #pragma unroll
    for (int i = 0; i < 12; i++) s_w[tid * 12 + i] = e[i] * inv;
  }
  __syncthreads();

  float4 a = make_float4(0.f, 0.f, 0.f, 0.f);
  #pragma unroll
  for (int pt = 0; pt < 12; pt++) {
    int s = head * 12 + pt;
    int l = pt >> 2;
    const float* V = (l == 0) ? V0 : (l == 1) ? V1 : V2;
    int Wl = 64 >> l;
    int Pl = Wl * Wl;
    int xi = s_xi[s], yi = s_yi[s];
    float fx = s_fx[s], fy = s_fy[s], w = s_w[s];
    const float* base = V + (size_t)b * Pl * CC;
    #pragma unroll
    for (int dy = 0; dy < 2; dy++) {
      #pragma unroll
      for (int dx = 0; dx < 2; dx++) {
        int X_ = xi + dx, Y_ = yi + dy;
        if (X_ >= 0 && X_ < Wl && Y_ >= 0 && Y_ < Wl) {
          float tw = w * (dx ? fx : 1.f - fx) * (dy ? fy : 1.f - fy);
          const float4 v = *(const float4*)(base + ((size_t)(Y_ * Wl + X_)) * CC + lane * 4);
          a.x += tw * v.x; a.y += tw * v.y; a.z += tw * v.z; a.w += tw * v.w;
        }
      }
    }
  }
  ushort4 r;
  r.x = f2bf(a.x); r.y = f2bf(a.y); r.z = f2bf(a.z); r.w = f2bf(a.w);
  *(ushort4*)(acc + (size_t)bn * 1024 + head * CC + lane * 4) = r;
}

// ------------------------------------------------- launch
extern "C" void kernel_launch(void* const* d_in, const int* in_sizes, int n_in,
                              void* d_out, int out_size, void* d_ws, size_t ws_size,
                              hipStream_t stream) {
  const float* S     = (const float*)d_in[0];
  const float* f0    = (const float*)d_in[1];
  const float* f1    = (const float*)d_in[2];
  const float* f2    = (const float*)d_in[3];
  const float* sim   = (const float*)d_in[4];
  const float* vw0   = (const float*)d_in[5];
  const float* vb0   = (const float*)d_in[6];
  const float* vw1   = (const float*)d_in[7];
  const float* vb1   = (const float*)d_in[8];
  const float* vw2   = (const float*)d_in[9];
  const float* vb2   = (const float*)d_in[10];
  const float* q_w   = (const float*)d_in[11];
  const float* q_b   = (const float*)d_in[12];
  const float* off_w = (const float*)d_in[13];
  const float* off_b = (const float*)d_in[14];
  const float* wgt_w = (const float*)d_in[15];
  const float* wgt_b = (const float*)d_in[16];
  const float* out_w = (const float*)d_in[17];
  const float* out_b = (const float*)d_in[18];
  const float* lnq_g = (const float*)d_in[19];
  const float* lnq_b = (const float*)d_in[20];
  const float* lno_g = (const float*)d_in[21];
  const float* lno_b = (const float*)d_in[22];
  const float* fc1_w = (const float*)d_in[23];
  const float* fc1_b = (const float*)d_in[24];
  const float* fc2_w = (const float*)d_in[25];
  const float* fc2_b = (const float*)d_in[26];

  char* p = (char*)d_ws;
  float* Sseq  = (float*)p;  p += 8388608;          // [8192][256] fp32
  float* Qraw  = (float*)p;  p += 8388608;          // alias Yraw
  float* V0    = (float*)p;  p += 8388608;          // alias Z
  float* V1    = (float*)p;  p += 2097152;
  float* V2    = (float*)p;  p += 524288;
  float* offwgt = (float*)p; p += 4718592;          // [8192][144] fp32
  float* bias144 = (float*)p; p += 1024;
  unsigned short* Sbf  = (unsigned short*)p; p += 4194304;   // [8192][256]
  unsigned short* Qbf  = (unsigned short*)p; p += 4194304;   // alias Zbf
  unsigned short* accbf = (unsigned short*)p; p += 16777216; // [8192][1024]; alias Xf*, h_bf
  unsigned short* q_wb  = (unsigned short*)p; p += 131072;
  unsigned short* owb   = (unsigned short*)p; p += 131072;
  unsigned short* vw0b  = (unsigned short*)p; p += 131072;
  unsigned short* vw1b  = (unsigned short*)p; p += 262144;
  unsigned short* vw2b  = (unsigned short*)p; p += 524288;
  unsigned short* out_wb = (unsigned short*)p; p += 524288;
  unsigned short* fc1_wb = (unsigned short*)p; p += 524288;
  unsigned short* fc2_wb = (unsigned short*)p; p += 524288;

  unsigned short* Xf0 = accbf;                       // [8192][256] bf16
  unsigned short* Xf1 = accbf + 2097152;             // [2048][512]
  unsigned short* Xf2 = accbf + 3145728;             // [512][1024]
  float* Yraw = Qraw;
  float* Z    = V0;
  unsigned short* Zbf = Qbf;
  unsigned short* hbf = accbf;
  float* outp = (float*)d_out;

  // 1. transposes + weight prep
  transpose_bf_k<<<dim3(128, 8, 2), dim3(32, 8), 0, stream>>>(S, Sseq, Sbf);
  prep_w_k<<<dim3(1024, 8), 256, 0, stream>>>(q_w, off_w, wgt_w, vw0, vw1, vw2,
      out_w, fc1_w, fc2_w, off_b, wgt_b,
      q_wb, owb, vw0b, vw1b, vw2b, out_wb, fc1_wb, fc2_wb, bias144);
  transpose_feat_k<<<dim3(128, 8, 2), dim3(32, 8), 0, stream>>>(f0, Xf0, 256, 4096);
  transpose_feat_k<<<dim3(32, 16, 2), dim3(32, 8), 0, stream>>>(f1, Xf1, 512, 1024);
  transpose_feat_k<<<dim3(8, 32, 2), dim3(32, 8), 0, stream>>>(f2, Xf2, 1024, 256);

  // 2. Qraw = Sseq @ q_w^T + q_b ; Q = LN(Qraw) -> bf16
  mgemm_k<0><<<dim3(2, 64), 256, 0, stream>>>(Sbf, q_wb, q_b, Qraw, nullptr, 256, 256, 256, nullptr, nullptr);
  ln_k<<<8192, 256, 0, stream>>>(Qraw, nullptr, lnq_g, lnq_b, nullptr, Qbf);

  // 3. off+wgt combined GEMM -> [8192][144] fp32
  mgemm_k<0><<<dim3(2, 64), 256, 0, stream>>>(Qbf, owb, bias144, offwgt, nullptr, 144, 256, 144, nullptr, nullptr);

  // 4. V projections
  mgemm_k<0><<<dim3(2, 64), 256, 0, stream>>>(Xf0, vw0b, vb0, V0, nullptr, 256, 256, 256, nullptr, nullptr);
  mgemm_k<0><<<dim3(2, 16), 256, 0, stream>>>(Xf1, vw1b, vb1, V1, nullptr, 256, 512, 256, nullptr, nullptr);
  mgemm_k<0><<<dim3(2, 4),  256, 0, stream>>>(Xf2, vw2b, vb2, V2, nullptr, 256, 1024, 256, nullptr, nullptr);

  // 5. sampling -> bf16 acc [8192][1024]
  sample_k<<<8192, 256, 0, stream>>>(offwgt, sim, V0, V1, V2, accbf);

  // 6. Yraw = acc @ out_w^T + out_b ; Z = LN(Sseq + Yraw) (fp32 + bf16)
  mgemm_k<0><<<dim3(2, 64), 256, 0, stream>>>(accbf, out_wb, out_b, Yraw, nullptr, 256, 1024, 256, nullptr, nullptr);
  ln_k<<<8192, 256, 0, stream>>>(Yraw, Sseq, lno_g, lno_b, Z, Zbf);

  // 7. h = gelu(Z @ fc1^T) -> bf16 ; out = T(Z + h @ fc2^T + fc2_b)
  mgemm_k<1><<<dim3(8, 64), 256, 0, stream>>>(Zbf, fc1_wb, fc1_b, nullptr, hbf, 1024, 256, 1024, nullptr, nullptr);
  mgemm_k<2><<<dim3(2, 64), 256, 0, stream>>>(hbf, fc2_wb, fc2_b, nullptr, nullptr, 256, 1024, 256, Z, outp);
}

// Round 3
// 313.319 us; speedup vs baseline: 2.9501x; 1.1858x over previous
//
#include <hip/hip_runtime.h>
#include <hip/hip_bf16.h>
#include <math.h>

#define NQ 4096
#define CC 256

typedef __attribute__((ext_vector_type(8))) short bfrag;
typedef __attribute__((ext_vector_type(4))) float ffrag;

__device__ inline unsigned short f2bf(float x) {
  __hip_bfloat16 h = __float2bfloat16(x);
  return *reinterpret_cast<unsigned short*>(&h);
}

__device__ inline void gload16(const void* g, void* l) {
  __builtin_amdgcn_global_load_lds(
      (const __attribute__((address_space(1))) void*)g,
      (__attribute__((address_space(3))) void*)l, 16, 0, 0);
}

// ================================================================= prep mega
// blocks [0,2048): S transpose (fp32+bf16)   [2048,4096): f0   [4096,5120): f1
// [5120,5632): f2   [5632,11008): weight fp32->bf16 casts
__device__ void tr_tile(const float* __restrict__ src, float* __restrict__ dstf,
                        unsigned short* __restrict__ dstb, int Cin, int P,
                        int p0, int c0, int b, float (*t)[33]) {
  int tid = threadIdx.x, tx = tid & 31, ty = tid >> 5;
  const float* Sb = src + (size_t)b * Cin * P;
  for (int i = ty; i < 32; i += 8)
    t[i][tx] = Sb[(size_t)(c0 + i) * P + p0 + tx];
  __syncthreads();
  size_t ob = (size_t)b * P * Cin;
  for (int i = ty; i < 32; i += 8) {
    float v = t[tx][i];
    size_t idx = ob + (size_t)(p0 + i) * Cin + c0 + tx;
    if (dstf) dstf[idx] = v;
    dstb[idx] = f2bf(v);
  }
}

__global__ __launch_bounds__(256)
void prep_all_k(const float* S, const float* f0, const float* f1, const float* f2,
                const float* q_w, const float* off_w, const float* wgt_w,
                const float* vw0, const float* vw1, const float* vw2,
                const float* out_w, const float* fc1_w, const float* fc2_w,
                const float* off_b, const float* wgt_b,
                float* Sseq, unsigned short* Sbf,
                unsigned short* Xf0, unsigned short* Xf1, unsigned short* Xf2,
                unsigned short* q_wb, unsigned short* owb,
                unsigned short* vw0b, unsigned short* vw1b, unsigned short* vw2b,
                unsigned short* out_wb, unsigned short* fc1_wb,
                unsigned short* fc2_wb, float* bias144) {
  __shared__ float t[32][33];
  int bid = blockIdx.x;
  if (bid < 2048) {
    int l = bid;
    tr_tile(S, Sseq, Sbf, 256, 4096, (l & 127) * 32, ((l >> 7) & 7) * 32, l >> 10, t);
  } else if (bid < 4096) {
    int l = bid - 2048;
    tr_tile(f0, nullptr, Xf0, 256, 4096, (l & 127) * 32, ((l >> 7) & 7) * 32, l >> 10, t);
  } else if (bid < 5120) {
    int l = bid - 4096;
    tr_tile(f1, nullptr, Xf1, 512, 1024, (l & 31) * 32, ((l >> 5) & 15) * 32, l >> 9, t);
  } else if (bid < 5632) {
    int l = bid - 5120;
    tr_tile(f2, nullptr, Xf2, 1024, 256, (l & 7) * 32, ((l >> 3) & 31) * 32, l >> 8, t);
  } else {
    int e = (bid - 5632) * 256 + threadIdx.x;
    if (e < 65536) q_wb[e] = f2bf(q_w[e]);
    else if (e < 131072) {
      int i = e - 65536;
      float v = (i < 24576) ? off_w[i] : (i < 36864 ? wgt_w[i - 24576] : 0.f);
      owb[i] = f2bf(v);
      if (i < 96) bias144[i] = off_b[i];
      else if (i < 144) bias144[i] = wgt_b[i - 96];
    } else if (e < 196608) { int i = e - 131072; vw0b[i] = f2bf(vw0[i]); }
    else if (e < 327680)  { int i = e - 196608; vw1b[i] = f2bf(vw1[i]); }
    else if (e < 589824)  { int i = e - 327680; vw2b[i] = f2bf(vw2[i]); }
    else if (e < 851968)  { int i = e - 589824; out_wb[i] = f2bf(out_w[i]); }
    else if (e < 1114112) { int i = e - 851968; fc1_wb[i] = f2bf(fc1_w[i]); }
    else if (e < 1376256) { int i = e - 1114112; fc2_wb[i] = f2bf(fc2_w[i]); }
  }
}

// ================================================================= GEMM body
// k-major LDS: slot = kc*R + r, 8 ushort per slot. 4 waves.
template<int BM, int BN, int WM, int WN, int EPI>
__device__ __forceinline__ void gemm_body(
    const unsigned short* __restrict__ A, const unsigned short* __restrict__ B,
    const float* __restrict__ bias, float* __restrict__ outf,
    unsigned short* __restrict__ outb, int N, int K, int ldo,
    const float* __restrict__ Zres, float* __restrict__ outT,
    int m0, int n0, unsigned short* As, unsigned short* Bs) {
  constexpr int MI = BM / (WM * 16), NI = BN / (WN * 16);
  constexpr int AI = BM / 16, BI = BN / 16, TI = AI + BI;
  constexpr int LBM = (BM == 32) ? 5 : (BM == 64) ? 6 : 7;
  constexpr int LBN = (BN == 128) ? 7 : 8;
  int tid = threadIdx.x, wave = tid >> 6, lane = tid & 63;
  int quad = lane >> 4, l16 = lane & 15;
  int wm = wave / WN, wn = wave % WN;
  const int mbase = wm * (BM / WM), nbase = wn * (BN / WN);

  ffrag acc[MI][NI];
  #pragma unroll
  for (int i = 0; i < MI; i++)
    #pragma unroll
    for (int j = 0; j < NI; j++) acc[i][j] = (ffrag)0.f;

  for (int k0 = 0; k0 < K; k0 += 32) {
    __syncthreads();
    for (int t = wave; t < TI; t += 4) {
      if (t < AI) {
        int s = t * 64 + lane;
        int kc = s >> LBM, r = s & (BM - 1);
        gload16(A + (size_t)(m0 + r) * K + k0 + kc * 8, (char*)As + t * 1024);
      } else {
        int s = (t - AI) * 64 + lane;
        int kc = s >> LBN, r = s & (BN - 1);
        gload16(B + (size_t)(n0 + r) * K + k0 + kc * 8, (char*)Bs + (t - AI) * 1024);
      }
    }
    __syncthreads();
    bfrag af[MI], bf[NI];
    #pragma unroll
    for (int mi = 0; mi < MI; mi++)
      af[mi] = *(const bfrag*)(As + (((quad << LBM) + mbase + mi * 16 + l16) << 3));
    #pragma unroll
    for (int ni = 0; ni < NI; ni++)
      bf[ni] = *(const bfrag*)(Bs + (((quad << LBN) + nbase + ni * 16 + l16) << 3));
    #pragma unroll
    for (int mi = 0; mi < MI; mi++)
      #pragma unroll
      for (int ni = 0; ni < NI; ni++)
        acc[mi][ni] = __builtin_amdgcn_mfma_f32_16x16x32_bf16(
            af[mi], bf[ni], acc[mi][ni], 0, 0, 0);
  }

  if (EPI == 0 || EPI == 1) {
    #pragma unroll
    for (int mi = 0; mi < MI; mi++) {
      int mrow = m0 + mbase + mi * 16 + quad * 4;
      #pragma unroll
      for (int ni = 0; ni < NI; ni++) {
        int n = n0 + nbase + ni * 16 + l16;
        if (n < N) {
          float bv = bias[n];
          #pragma unroll
          for (int r = 0; r < 4; r++) {
            float v = acc[mi][ni][r] + bv;
            if (EPI == 1) {
              v = 0.5f * v * (1.f + erff(v * 0.70710678118654752f));
              outb[(size_t)(mrow + r) * ldo + n] = f2bf(v);
            } else {
              outf[(size_t)(mrow + r) * ldo + n] = v;
            }
          }
        }
      }
    }
  } else {  // EPI 2: + bias + Zres, transposed float4 store along m
    #pragma unroll
    for (int mi = 0; mi < MI; mi++) {
      int mrow = m0 + mbase + mi * 16 + quad * 4;
      int bb = mrow >> 12, q0 = mrow & (NQ - 1);
      #pragma unroll
      for (int ni = 0; ni < NI; ni++) {
        int n = n0 + nbase + ni * 16 + l16;
        float bv = bias[n];
        float4 v;
        v.x = acc[mi][ni][0] + bv + Zres[(size_t)(mrow + 0) * CC + n];
        v.y = acc[mi][ni][1] + bv + Zres[(size_t)(mrow + 1) * CC + n];
        v.z = acc[mi][ni][2] + bv + Zres[(size_t)(mrow + 2) * CC + n];
        v.w = acc[mi][ni][3] + bv + Zres[(size_t)(mrow + 3) * CC + n];
        *(float4*)(outT + ((size_t)(bb * CC + n)) * NQ + q0) = v;
      }
    }
  }
}

// ================================================================= GEMM + LN
// BM=32, BN=256: full LN rows per block. grid = 256 blocks (M/32).
template<bool RES>
__global__ __launch_bounds__(256)
void gemm_ln_k(const unsigned short* __restrict__ A,
               const unsigned short* __restrict__ B,
               const float* __restrict__ bias, const float* __restrict__ res,
               float* __restrict__ outf, unsigned short* __restrict__ outb,
               const float* __restrict__ g, const float* __restrict__ be, int K) {
  __shared__ __attribute__((aligned(16))) char sm[35840];
  unsigned short* As = (unsigned short*)sm;            // [0, 2048)
  unsigned short* Bs = (unsigned short*)(sm + 2048);   // [2048, 20480)
  float* L  = (float*)sm;                              // [0, 33792) 32x264
  float* gs = (float*)(sm + 33792);
  float* bs = gs + 256;

  int tid = threadIdx.x, wave = tid >> 6, lane = tid & 63;
  int quad = lane >> 4, l16 = lane & 15;
  int m0 = blockIdx.x * 32;
  gs[tid] = g[tid];
  bs[tid] = be[tid];

  ffrag acc[2][4];
  #pragma unroll
  for (int i = 0; i < 2; i++)
    #pragma unroll
    for (int j = 0; j < 4; j++) acc[i][j] = (ffrag)0.f;

  for (int k0 = 0; k0 < K; k0 += 32) {
    __syncthreads();
    for (int t = wave; t < 18; t += 4) {
      if (t < 2) {
        int s = t * 64 + lane;
        int kc = s >> 5, r = s & 31;
        gload16(A + (size_t)(m0 + r) * K + k0 + kc * 8, (char*)As + t * 1024);
      } else {
        int s = (t - 2) * 64 + lane;
        int kc = s >> 8, r = s & 255;
        gload16(B + (size_t)r * K + k0 + kc * 8, (char*)Bs + (t - 2) * 1024);
      }
    }
    __syncthreads();
    bfrag af[2], bf[4];
    #pragma unroll
    for (int mi = 0; mi < 2; mi++)
      af[mi] = *(const bfrag*)(As + (((quad << 5) + mi * 16 + l16) << 3));
    #pragma unroll
    for (int ni = 0; ni < 4; ni++)
      bf[ni] = *(const bfrag*)(Bs + (((quad << 8) + wave * 64 + ni * 16 + l16) << 3));
    #pragma unroll
    for (int mi = 0; mi < 2; mi++)
      #pragma unroll
      for (int ni = 0; ni < 4; ni++)
        acc[mi][ni] = __builtin_amdgcn_mfma_f32_16x16x32_bf16(
            af[mi], bf[ni], acc[mi][ni], 0, 0, 0);
  }
  __syncthreads();

  // raw result (+bias, +residual) -> LDS rows
  #pragma unroll
  for (int mi = 0; mi < 2; mi++) {
    int row = mi * 16 + quad * 4;
    #pragma unroll
    for (int ni = 0; ni < 4; ni++) {
      int col = wave * 64 + ni * 16 + l16;
      float bv = bias[col];
      #pragma unroll
      for (int r = 0; r < 4; r++) {
        float v = acc[mi][ni][r] + bv;
        if (RES) v += res[(size_t)(m0 + row + r) * CC + col];
        L[(row + r) * 264 + col] = v;
      }
    }
  }
  __syncthreads();

  int row = tid >> 3, j = tid & 7;
  int seg = ((j + row) & 7) * 32;
  const float* Lr = L + row * 264 + seg;
  float s1 = 0.f, s2 = 0.f;
  #pragma unroll
  for (int i = 0; i < 8; i++) {
    float4 t4 = *(const float4*)(Lr + i * 4);
    s1 += t4.x + t4.y + t4.z + t4.w;
    s2 += t4.x * t4.x + t4.y * t4.y + t4.z * t4.z + t4.w * t4.w;
  }
  #pragma unroll
  for (int o = 1; o < 8; o <<= 1) {
    s1 += __shfl_xor(s1, o);
    s2 += __shfl_xor(s2, o);
  }
  float mu = s1 * (1.f / 256.f);
  float var = s2 * (1.f / 256.f) - mu * mu;
  float rs = rsqrtf(var + 1e-5f);
  int gm = m0 + row;
  #pragma unroll
  for (int i = 0; i < 8; i++) {
    int col = seg + i * 4;
    float4 t4 = *(const float4*)(Lr + i * 4);
    float4 y;
    y.x = (t4.x - mu) * rs * gs[col + 0] + bs[col + 0];
    y.y = (t4.y - mu) * rs * gs[col + 1] + bs[col + 1];
    y.z = (t4.z - mu) * rs * gs[col + 2] + bs[col + 2];
    y.w = (t4.w - mu) * rs * gs[col + 3] + bs[col + 3];
    ushort4 ub;
    ub.x = f2bf(y.x); ub.y = f2bf(y.y); ub.z = f2bf(y.z); ub.w = f2bf(y.w);
    *(ushort4*)(outb + (size_t)gm * CC + col) = ub;
    if (RES) *(float4*)(outf + (size_t)gm * CC + col) = y;
  }
}

// ================================================================= wrappers
__global__ __launch_bounds__(256)
void vproj_k(const unsigned short* Xf0, const unsigned short* Xf1,
             const unsigned short* Xf2, const unsigned short* vw0b,
             const unsigned short* vw1b, const unsigned short* vw2b,
             const float* vb0, const float* vb1, const float* vb2,
             float* V0, float* V1, float* V2) {
  __shared__ __attribute__((aligned(16))) unsigned short As[2048];
  __shared__ __attribute__((aligned(16))) unsigned short Bs[4096];
  int bid = blockIdx.x;
  const unsigned short *A, *B; const float* bias; float* out; int K, lb;
  if (bid < 256)      { A = Xf0; B = vw0b; bias = vb0; out = V0; K = 256;  lb = bid; }
  else if (bid < 320) { A = Xf1; B = vw1b; bias = vb1; out = V1; K = 512;  lb = bid - 256; }
  else                { A = Xf2; B = vw2b; bias = vb2; out = V2; K = 1024; lb = bid - 320; }
  int n0 = (lb & 1) * 128, m0 = (lb >> 1) * 64;
  gemm_body<64, 128, 2, 2, 0>(A, B, bias, out, nullptr, 256, K, 256,
                              nullptr, nullptr, m0, n0, As, Bs);
}

__global__ __launch_bounds__(256)
void offwgt_k(const unsigned short* Qbf, const unsigned short* owb,
              const float* bias144, float* offwgt) {
  __shared__ __attribute__((aligned(16))) unsigned short As[2048];
  __shared__ __attribute__((aligned(16))) unsigned short Bs[4096];
  gemm_body<64, 128, 2, 2, 0>(Qbf, owb, bias144, offwgt, nullptr, 144, 256, 144,
                              nullptr, nullptr, blockIdx.y * 64, blockIdx.x * 128, As, Bs);
}

__global__ __launch_bounds__(256)
void fc1_k(const unsigned short* Zbf, const unsigned short* fc1_wb,
           const float* fc1_b, unsigned short* hbf) {
  __shared__ __attribute__((aligned(16))) unsigned short As[4096];
  __shared__ __attribute__((aligned(16))) unsigned short Bs[4096];
  gemm_body<128, 128, 2, 2, 1>(Zbf, fc1_wb, fc1_b, nullptr, hbf, 1024, 256, 1024,
                               nullptr, nullptr, blockIdx.y * 128, blockIdx.x * 128, As, Bs);
}

__global__ __launch_bounds__(256)
void fc2_k(const unsigned short* hbf, const unsigned short* fc2_wb,
           const float* fc2_b, const float* Z, float* outp) {
  __shared__ __attribute__((aligned(16))) unsigned short As[2048];
  __shared__ __attribute__((aligned(16))) unsigned short Bs[4096];
  gemm_body<64, 128, 2, 2, 2>(hbf, fc2_wb, fc2_b, nullptr, nullptr, 256, 1024, 256,
                              Z, outp, blockIdx.y * 64, blockIdx.x * 128, As, Bs);
}

// ================================================================= sampling
__global__ __launch_bounds__(256)
void sample_k(const float* __restrict__ ow, const float* __restrict__ sim,
              const float* __restrict__ V0, const float* __restrict__ V1,
              const float* __restrict__ V2, unsigned short* __restrict__ acc) {
  int bn = blockIdx.x;
  int q = ((bn & 7) << 10) | (bn >> 3);   // XCD-locality swizzle
  int b = q >> 12, n = q & (NQ - 1);
  int tid = threadIdx.x, head = tid >> 6, lane = tid & 63;

  __shared__ float s_w[48];
  __shared__ int   s_xy[48][2];
  __shared__ float s_f[48][2];
  __shared__ int   s_off[192];
  __shared__ float s_twt[192];

  if (tid < 48) {
    int hh = tid / 12, pt = tid % 12, l = pt >> 2, mm = pt & 3;
    int oidx = (hh * 3 + l) * 4 + mm;
    float offx = ow[(size_t)q * 144 + oidx * 2 + 0];
    float offy = ow[(size_t)q * 144 + oidx * 2 + 1];
    float refx = ((n & 63) + 0.5f) * (1.f / 64.f);
    float refy = ((n >> 6) + 0.5f) * (1.f / 64.f);
    float gx = tanhf((refx + offx) * 2.f - 1.f);
    float gy = tanhf((refy + offy) * 2.f - 1.f);
    gx = fminf(1.f, fmaxf(-1.f, gx));
    gy = fminf(1.f, fmaxf(-1.f, gy));
    int Wl = 64 >> l;
    float x = (gx + 1.f) * 0.5f * (float)(Wl - 1);
    float y = (gy + 1.f) * 0.5f * (float)(Wl - 1);
    float x0 = floorf(x), y0 = floorf(y);
    s_xy[tid][0] = (int)x0;
    s_xy[tid][1] = (int)y0;
    s_f[tid][0] = x - x0;
    s_f[tid][1] = y - y0;
    s_w[tid] = ow[(size_t)q * 144 + 96 + oidx] * (sim[q] + 0.001f);
  }
  __syncthreads();
  if (tid < 4) {
    float mx = -1e30f;
    #pragma unroll
    for (int i = 0; i < 12; i++) mx = fmaxf(mx, s_w[tid * 12 + i]);
    float e[12], ssum = 0.f;
    #pragma unroll
    for (int i = 0; i < 12; i++) { e[i] = expf(s_w[tid * 12 + i] - mx); ssum += e[i]; }
    float inv = 1.f / ssum;
    #pragma unroll
    for (int i = 0; i < 12; i++) s_w[tid * 12 + i] = e[i] * inv;
  }
  __syncthreads();
  if (tid < 192) {
    int s = tid >> 2, tap = tid & 3;
    int l = (s % 12) >> 2;
    int Wl = 64 >> l;
    int X = s_xy[s][0] + (tap & 1), Y = s_xy[s][1] + (tap >> 1);
    bool valid = (X >= 0 && X < Wl && Y >= 0 && Y < Wl);
    float wx = (tap & 1) ? s_f[s][0] : 1.f - s_f[s][0];
    float wy = (tap >> 1) ? s_f[s][1] : 1.f - s_f[s][1];
    s_twt[tid] = valid ? s_w[s] * wx * wy : 0.f;
    int Xc = min(max(X, 0), Wl - 1), Yc = min(max(Y, 0), Wl - 1);
    s_off[tid] = (Yc * Wl + Xc) << 8;
  }
  __syncthreads();

  const float* B0 = V0 + (size_t)b * 4096 * CC;
  const float* B1 = V1 + (size_t)b * 1024 * CC;
  const float* B2 = V2 + (size_t)b * 256 * CC;
  int lane4 = lane * 4;
  float4 a = make_float4(0.f, 0.f, 0.f, 0.f);
  #pragma unroll
  for (int pt = 0; pt < 12; pt++) {
    const float* base = (pt < 4) ? B0 : (pt < 8) ? B1 : B2;
    int s = head * 12 + pt;
    #pragma unroll
    for (int tap = 0; tap < 4; tap++) {
      int off = s_off[s * 4 + tap];
      float w = s_twt[s * 4 + tap];
      const float4 v = *(const float4*)(base + off + lane4);
      a.x += w * v.x; a.y += w * v.y; a.z += w * v.z; a.w += w * v.w;
    }
  }
  ushort4 r;
  r.x = f2bf(a.x); r.y = f2bf(a.y); r.z = f2bf(a.z); r.w = f2bf(a.w);
  *(ushort4*)(acc + (size_t)q * 1024 + head * CC + lane4) = r;
}

// ================================================================= launch
extern "C" void kernel_launch(void* const* d_in, const int* in_sizes, int n_in,
                              void* d_out, int out_size, void* d_ws, size_t ws_size,
                              hipStream_t stream) {
  const float* S     = (const float*)d_in[0];
  const float* f0    = (const float*)d_in[1];
  const float* f1    = (const float*)d_in[2];
  const float* f2    = (const float*)d_in[3];
  const float* sim   = (const float*)d_in[4];
  const float* vw0   = (const float*)d_in[5];
  const float* vb0   = (const float*)d_in[6];
  const float* vw1   = (const float*)d_in[7];
  const float* vb1   = (const float*)d_in[8];
  const float* vw2   = (const float*)d_in[9];
  const float* vb2   = (const float*)d_in[10];
  const float* q_w   = (const float*)d_in[11];
  const float* q_b   = (const float*)d_in[12];
  const float* off_w = (const float*)d_in[13];
  const float* off_b = (const float*)d_in[14];
  const float* wgt_w = (const float*)d_in[15];
  const float* wgt_b = (const float*)d_in[16];
  const float* out_w = (const float*)d_in[17];
  const float* out_b = (const float*)d_in[18];
  const float* lnq_g = (const float*)d_in[19];
  const float* lnq_b = (const float*)d_in[20];
  const float* lno_g = (const float*)d_in[21];
  const float* lno_b = (const float*)d_in[22];
  const float* fc1_w = (const float*)d_in[23];
  const float* fc1_b = (const float*)d_in[24];
  const float* fc2_w = (const float*)d_in[25];
  const float* fc2_b = (const float*)d_in[26];

  char* p = (char*)d_ws;
  float* Sseq   = (float*)p; p += 8388608;               // [8192][256] fp32
  float* V0     = (float*)p; p += 8388608;               // alias Z
  float* V1     = (float*)p; p += 2097152;
  float* V2     = (float*)p; p += 524288;
  float* offwgt = (float*)p; p += 4718592;               // [8192][144]
  float* bias144 = (float*)p; p += 1024;
  unsigned short* Sbf   = (unsigned short*)p; p += 4194304;
  unsigned short* Qbf   = (unsigned short*)p; p += 4194304;   // alias Zbf
  unsigned short* accbf = (unsigned short*)p; p += 16777216;  // alias Xf*, hbf
  unsigned short* q_wb   = (unsigned short*)p; p += 131072;
  unsigned short* owb    = (unsigned short*)p; p += 131072;
  unsigned short* vw0b   = (unsigned short*)p; p += 131072;
  unsigned short* vw1b   = (unsigned short*)p; p += 262144;
  unsigned short* vw2b   = (unsigned short*)p; p += 524288;
  unsigned short* out_wb = (unsigned short*)p; p += 524288;
  unsigned short* fc1_wb = (unsigned short*)p; p += 524288;
  unsigned short* fc2_wb = (unsigned short*)p; p += 524288;

  unsigned short* Xf0 = accbf;
  unsigned short* Xf1 = accbf + 2097152;
  unsigned short* Xf2 = accbf + 3145728;
  float* Z = V0;
  unsigned short* Zbf = Qbf;
  unsigned short* hbf = accbf;
  float* outp = (float*)d_out;

  prep_all_k<<<11008, 256, 0, stream>>>(S, f0, f1, f2, q_w, off_w, wgt_w,
      vw0, vw1, vw2, out_w, fc1_w, fc2_w, off_b, wgt_b,
      Sseq, Sbf, Xf0, Xf1, Xf2, q_wb, owb, vw0b, vw1b, vw2b, out_wb,
      fc1_wb, fc2_wb, bias144);

  gemm_ln_k<false><<<256, 256, 0, stream>>>(Sbf, q_wb, q_b, nullptr,
      nullptr, Qbf, lnq_g, lnq_b, 256);

  vproj_k<<<336, 256, 0, stream>>>(Xf0, Xf1, Xf2, vw0b, vw1b, vw2b,
      vb0, vb1, vb2, V0, V1, V2);

  offwgt_k<<<dim3(2, 128), 256, 0, stream>>>(Qbf, owb, bias144, offwgt);

  sample_k<<<8192, 256, 0, stream>>>(offwgt, sim, V0, V1, V2, accbf);

  gemm_ln_k<true><<<256, 256, 0, stream>>>(accbf, out_wb, out_b, Sseq,
      Z, Zbf, lno_g, lno_b, 1024);

  fc1_k<<<dim3(8, 64), 256, 0, stream>>>(Zbf, fc1_wb, fc1_b, hbf);

  fc2_k<<<dim3(2, 128), 256, 0, stream>>>(hbf, fc2_wb, fc2_b, Z, outp);
}

// Round 4
// 296.071 us; speedup vs baseline: 3.1219x; 1.0583x over previous
//
#include <hip/hip_runtime.h>
#include <hip/hip_bf16.h>
#include <math.h>

#define NQ 4096
#define CC 256

typedef __attribute__((ext_vector_type(8))) short bfrag;
typedef __attribute__((ext_vector_type(4))) float ffrag;

__device__ inline unsigned short f2bf(float x) {
  __hip_bfloat16 h = __float2bfloat16(x);
  return *reinterpret_cast<unsigned short*>(&h);
}

__device__ inline void gload16(const void* g, void* l) {
  __builtin_amdgcn_global_load_lds(
      (const __attribute__((address_space(1))) void*)g,
      (__attribute__((address_space(3))) void*)l, 16, 0, 0);
}

// ================================================================= prep mega
// 64x64 float4 transpose tile. t[64][73] fp32 (pad 73 -> 2-way max on col reads)
__device__ void tr64(const float* __restrict__ src, float* __restrict__ dstf,
                     unsigned short* __restrict__ dstb, int Cin, int P,
                     int p0, int c0, int b, float (*t)[73]) {
  int tid = threadIdx.x;
  int rx = tid & 15, ry = tid >> 4;
  const float* Sb = src + (size_t)b * Cin * P + p0 + rx * 4;
  #pragma unroll
  for (int i = 0; i < 4; i++) {
    int r = ry + i * 16;
    float4 v = *(const float4*)(Sb + (size_t)(c0 + r) * P);
    t[r][rx * 4 + 0] = v.x; t[r][rx * 4 + 1] = v.y;
    t[r][rx * 4 + 2] = v.z; t[r][rx * 4 + 3] = v.w;
  }
  __syncthreads();
  size_t ob = (size_t)b * P * Cin;
  #pragma unroll
  for (int i = 0; i < 4; i++) {
    int pr = ry + i * 16;
    float x0 = t[rx * 4 + 0][pr], x1 = t[rx * 4 + 1][pr];
    float x2 = t[rx * 4 + 2][pr], x3 = t[rx * 4 + 3][pr];
    size_t idx = ob + (size_t)(p0 + pr) * Cin + c0 + rx * 4;
    if (dstf) { float4 f4 = make_float4(x0, x1, x2, x3); *(float4*)(dstf + idx) = f4; }
    ushort4 u4;
    u4.x = f2bf(x0); u4.y = f2bf(x1); u4.z = f2bf(x2); u4.w = f2bf(x3);
    *(ushort4*)(dstb + idx) = u4;
  }
}

// blocks: [0,512) S  [512,1024) f0  [1024,1280) f1  [1280,1408) f2
//         [1408,2688) weight float4 casts  [2688,2944) off/wgt + bias144
__global__ __launch_bounds__(256)
void prep_all_k(const float* S, const float* f0, const float* f1, const float* f2,
                const float* q_w, const float* off_w, const float* wgt_w,
                const float* vw0, const float* vw1, const float* vw2,
                const float* out_w, const float* fc1_w, const float* fc2_w,
                const float* off_b, const float* wgt_b,
                float* Sseq, unsigned short* Sbf,
                unsigned short* Xf0, unsigned short* Xf1, unsigned short* Xf2,
                unsigned short* q_wb, unsigned short* owb,
                unsigned short* vw0b, unsigned short* vw1b, unsigned short* vw2b,
                unsigned short* out_wb, unsigned short* fc1_wb,
                unsigned short* fc2_wb, float* bias144) {
  __shared__ float t[64][73];
  int bid = blockIdx.x;
  if (bid < 512) {
    int l = bid;
    tr64(S, Sseq, Sbf, 256, 4096, (l & 63) * 64, ((l >> 6) & 3) * 64, l >> 8, t);
  } else if (bid < 1024) {
    int l = bid - 512;
    tr64(f0, nullptr, Xf0, 256, 4096, (l & 63) * 64, ((l >> 6) & 3) * 64, l >> 8, t);
  } else if (bid < 1280) {
    int l = bid - 1024;
    tr64(f1, nullptr, Xf1, 512, 1024, (l & 15) * 64, ((l >> 4) & 7) * 64, l >> 7, t);
  } else if (bid < 1408) {
    int l = bid - 1280;
    tr64(f2, nullptr, Xf2, 1024, 256, (l & 3) * 64, ((l >> 2) & 15) * 64, l >> 6, t);
  } else if (bid < 2688) {
    int i4 = (bid - 1408) * 256 + threadIdx.x;
    const float* src; unsigned short* dst;
    if (i4 < 16384)       { src = q_w;   dst = q_wb; }
    else if (i4 < 32768)  { i4 -= 16384;  src = vw0;   dst = vw0b; }
    else if (i4 < 65536)  { i4 -= 32768;  src = vw1;   dst = vw1b; }
    else if (i4 < 131072) { i4 -= 65536;  src = vw2;   dst = vw2b; }
    else if (i4 < 196608) { i4 -= 131072; src = out_w; dst = out_wb; }
    else if (i4 < 262144) { i4 -= 196608; src = fc1_w; dst = fc1_wb; }
    else                  { i4 -= 262144; src = fc2_w; dst = fc2_wb; }
    float4 v = ((const float4*)src)[i4];
    ushort4 u; u.x = f2bf(v.x); u.y = f2bf(v.y); u.z = f2bf(v.z); u.w = f2bf(v.w);
    ((ushort4*)dst)[i4] = u;
  } else {
    int e = (bid - 2688) * 256 + threadIdx.x;
    float v = (e < 24576) ? off_w[e] : (e < 36864 ? wgt_w[e - 24576] : 0.f);
    owb[e] = f2bf(v);
    if (e < 96) bias144[e] = off_b[e];
    else if (e < 144) bias144[e] = wgt_b[e - 96];
  }
}

// ================================================================= GEMM body
// BK=64, k-major LDS slots of 8 ushorts: slot = kc*R + r.
template<int BM, int BN, int WM, int WN, int EPI>
__device__ __forceinline__ void gemm_body(
    const unsigned short* __restrict__ A, const unsigned short* __restrict__ B,
    const float* __restrict__ bias, float* __restrict__ outf,
    unsigned short* __restrict__ outb, int N, int K, int ldo,
    const float* __restrict__ Zres, float* __restrict__ outT,
    int m0, int n0, unsigned short* As, unsigned short* Bs) {
  constexpr int MI = BM / (WM * 16), NI = BN / (WN * 16);
  constexpr int TA = BM / 8, TB = BN / 8;
  constexpr int LBM = (BM == 32) ? 5 : (BM == 64) ? 6 : 7;
  constexpr int LBN = (BN == 64) ? 6 : (BN == 128) ? 7 : 8;
  int tid = threadIdx.x, wave = tid >> 6, lane = tid & 63;
  int quad = lane >> 4, l16 = lane & 15;
  int wm = wave / WN, wn = wave % WN;
  const int mbase = wm * (BM / WM), nbase = wn * (BN / WN);

  ffrag acc[MI][NI];
  #pragma unroll
  for (int i = 0; i < MI; i++)
    #pragma unroll
    for (int j = 0; j < NI; j++) acc[i][j] = (ffrag)0.f;

  for (int k0 = 0; k0 < K; k0 += 64) {
    __syncthreads();
    for (int t = wave; t < TA + TB; t += 4) {
      if (t < TA) {
        int s = t * 64 + lane;
        int kc = s >> LBM, r = s & (BM - 1);
        gload16(A + (size_t)(m0 + r) * K + k0 + kc * 8, (char*)As + t * 1024);
      } else {
        int s = (t - TA) * 64 + lane;
        int kc = s >> LBN, r = s & (BN - 1);
        gload16(B + (size_t)(n0 + r) * K + k0 + kc * 8, (char*)Bs + (t - TA) * 1024);
      }
    }
    __syncthreads();
    #pragma unroll
    for (int ks = 0; ks < 2; ks++) {
      bfrag af[MI], bf[NI];
      #pragma unroll
      for (int mi = 0; mi < MI; mi++)
        af[mi] = *(const bfrag*)(As + ((((ks * 4 + quad) << LBM) + mbase + mi * 16 + l16) << 3));
      #pragma unroll
      for (int ni = 0; ni < NI; ni++)
        bf[ni] = *(const bfrag*)(Bs + ((((ks * 4 + quad) << LBN) + nbase + ni * 16 + l16) << 3));
      #pragma unroll
      for (int mi = 0; mi < MI; mi++)
        #pragma unroll
        for (int ni = 0; ni < NI; ni++)
          acc[mi][ni] = __builtin_amdgcn_mfma_f32_16x16x32_bf16(
              af[mi], bf[ni], acc[mi][ni], 0, 0, 0);
    }
  }

  if (EPI == 2) {  // + bias + Zres, transposed float4 store along m
    #pragma unroll
    for (int mi = 0; mi < MI; mi++) {
      int mrow = m0 + mbase + mi * 16 + quad * 4;
      int bb = mrow >> 12, q0 = mrow & (NQ - 1);
      #pragma unroll
      for (int ni = 0; ni < NI; ni++) {
        int n = n0 + nbase + ni * 16 + l16;
        float bv = bias[n];
        float4 v;
        v.x = acc[mi][ni][0] + bv + Zres[(size_t)(mrow + 0) * CC + n];
        v.y = acc[mi][ni][1] + bv + Zres[(size_t)(mrow + 1) * CC + n];
        v.z = acc[mi][ni][2] + bv + Zres[(size_t)(mrow + 2) * CC + n];
        v.w = acc[mi][ni][3] + bv + Zres[(size_t)(mrow + 3) * CC + n];
        *(float4*)(outT + ((size_t)(bb * CC + n)) * NQ + q0) = v;
      }
    }
  } else {
    #pragma unroll
    for (int mi = 0; mi < MI; mi++) {
      int mrow = m0 + mbase + mi * 16 + quad * 4;
      #pragma unroll
      for (int ni = 0; ni < NI; ni++) {
        int n = n0 + nbase + ni * 16 + l16;
        if (n < N) {
          float bv = bias[n];
          #pragma unroll
          for (int r = 0; r < 4; r++) {
            float v = acc[mi][ni][r] + bv;
            if (EPI == 1) {
              v = 0.5f * v * (1.f + erff(v * 0.70710678118654752f));
              outb[(size_t)(mrow + r) * ldo + n] = f2bf(v);
            } else if (EPI == 3) {
              outb[(size_t)(mrow + r) * ldo + n] = f2bf(v);
            } else {
              outf[(size_t)(mrow + r) * ldo + n] = v;
            }
          }
        }
      }
    }
  }
}

// ================================================================= GEMM + LN
// BM=32, BN=256(full), BK=64. LDS: As 4K | Bs 32K, then L 32x264 fp32.
template<bool RES>
__device__ __forceinline__ void gemm_ln_body(
    const unsigned short* __restrict__ A, const unsigned short* __restrict__ B,
    const float* __restrict__ bias, const float* __restrict__ res,
    float* __restrict__ outf, unsigned short* __restrict__ outb,
    const float* __restrict__ g, const float* __restrict__ be,
    int K, int m0, char* sm) {
  unsigned short* As = (unsigned short*)sm;
  unsigned short* Bs = (unsigned short*)(sm + 4096);
  float* L = (float*)sm;

  int tid = threadIdx.x, wave = tid >> 6, lane = tid & 63;
  int quad = lane >> 4, l16 = lane & 15;

  ffrag acc[2][4];
  #pragma unroll
  for (int i = 0; i < 2; i++)
    #pragma unroll
    for (int j = 0; j < 4; j++) acc[i][j] = (ffrag)0.f;

  for (int k0 = 0; k0 < K; k0 += 64) {
    __syncthreads();
    for (int t = wave; t < 36; t += 4) {
      if (t < 4) {
        int s = t * 64 + lane;
        int kc = s >> 5, r = s & 31;
        gload16(A + (size_t)(m0 + r) * K + k0 + kc * 8, sm + t * 1024);
      } else {
        int s = (t - 4) * 64 + lane;
        int kc = s >> 8, r = s & 255;
        gload16(B + (size_t)r * K + k0 + kc * 8, sm + 4096 + (t - 4) * 1024);
      }
    }
    __syncthreads();
    #pragma unroll
    for (int ks = 0; ks < 2; ks++) {
      bfrag af[2], bf[4];
      #pragma unroll
      for (int mi = 0; mi < 2; mi++)
        af[mi] = *(const bfrag*)(As + ((((ks * 4 + quad) << 5) + mi * 16 + l16) << 3));
      #pragma unroll
      for (int ni = 0; ni < 4; ni++)
        bf[ni] = *(const bfrag*)(Bs + ((((ks * 4 + quad) << 8) + wave * 64 + ni * 16 + l16) << 3));
      #pragma unroll
      for (int mi = 0; mi < 2; mi++)
        #pragma unroll
        for (int ni = 0; ni < 4; ni++)
          acc[mi][ni] = __builtin_amdgcn_mfma_f32_16x16x32_bf16(
              af[mi], bf[ni], acc[mi][ni], 0, 0, 0);
    }
  }
  __syncthreads();

  #pragma unroll
  for (int mi = 0; mi < 2; mi++) {
    int row = mi * 16 + quad * 4;
    #pragma unroll
    for (int ni = 0; ni < 4; ni++) {
      int col = wave * 64 + ni * 16 + l16;
      float bv = bias[col];
      #pragma unroll
      for (int r = 0; r < 4; r++) {
        float v = acc[mi][ni][r] + bv;
        if (RES) v += res[(size_t)(m0 + row + r) * CC + col];
        L[(row + r) * 264 + col] = v;
      }
    }
  }
  __syncthreads();

  int row = tid >> 3, j = tid & 7;
  int seg = ((j + row) & 7) * 32;
  const float* Lr = L + row * 264 + seg;
  float s1 = 0.f, s2 = 0.f;
  #pragma unroll
  for (int i = 0; i < 8; i++) {
    float4 t4 = *(const float4*)(Lr + i * 4);
    s1 += t4.x + t4.y + t4.z + t4.w;
    s2 += t4.x * t4.x + t4.y * t4.y + t4.z * t4.z + t4.w * t4.w;
  }
  #pragma unroll
  for (int o = 1; o < 8; o <<= 1) {
    s1 += __shfl_xor(s1, o);
    s2 += __shfl_xor(s2, o);
  }
  float mu = s1 * (1.f / 256.f);
  float var = s2 * (1.f / 256.f) - mu * mu;
  float rs = rsqrtf(var + 1e-5f);
  int gm = m0 + row;
  #pragma unroll
  for (int i = 0; i < 8; i++) {
    int col = seg + i * 4;
    float4 t4 = *(const float4*)(Lr + i * 4);
    float4 gg = *(const float4*)(g + col);
    float4 bb4 = *(const float4*)(be + col);
    float4 y;
    y.x = (t4.x - mu) * rs * gg.x + bb4.x;
    y.y = (t4.y - mu) * rs * gg.y + bb4.y;
    y.z = (t4.z - mu) * rs * gg.z + bb4.z;
    y.w = (t4.w - mu) * rs * gg.w + bb4.w;
    ushort4 ub;
    ub.x = f2bf(y.x); ub.y = f2bf(y.y); ub.z = f2bf(y.z); ub.w = f2bf(y.w);
    *(ushort4*)(outb + (size_t)gm * CC + col) = ub;
    if (RES) *(float4*)(outf + (size_t)gm * CC + col) = y;
  }
}

// ================================================================= kernels
// fused: blocks [0,256) = Q-proj+LN ; [256,592) = V projections (bf16 out)
__global__ __launch_bounds__(256)
void qv_k(const unsigned short* Sbf, const unsigned short* q_wb, const float* q_b,
          const float* lnq_g, const float* lnq_b, unsigned short* Qbf,
          const unsigned short* Xf0, const unsigned short* Xf1,
          const unsigned short* Xf2, const unsigned short* vw0b,
          const unsigned short* vw1b, const unsigned short* vw2b,
          const float* vb0, const float* vb1, const float* vb2,
          unsigned short* V0b, unsigned short* V1b, unsigned short* V2b) {
  __shared__ __attribute__((aligned(16))) char sm[36864];
  int bid = blockIdx.x;
  if (bid < 256) {
    gemm_ln_body<false>(Sbf, q_wb, q_b, nullptr, nullptr, Qbf,
                        lnq_g, lnq_b, 256, bid * 32, sm);
  } else {
    int lb = bid - 256;
    const unsigned short *A, *B; const float* bias; unsigned short* out; int K;
    if (lb < 256)      { A = Xf0; B = vw0b; bias = vb0; out = V0b; K = 256; }
    else if (lb < 320) { A = Xf1; B = vw1b; bias = vb1; out = V1b; K = 512;  lb -= 256; }
    else               { A = Xf2; B = vw2b; bias = vb2; out = V2b; K = 1024; lb -= 320; }
    int n0 = (lb & 1) * 128, m0 = (lb >> 1) * 64;
    gemm_body<64, 128, 2, 2, 3>(A, B, bias, nullptr, out, 256, K, 256,
                                nullptr, nullptr, m0, n0,
                                (unsigned short*)sm, (unsigned short*)(sm + 8192));
  }
}

__global__ __launch_bounds__(256)
void outln_k(const unsigned short* accbf, const unsigned short* out_wb,
             const float* out_b, const float* Sseq, float* Z,
             unsigned short* Zbf, const float* lno_g, const float* lno_b) {
  __shared__ __attribute__((aligned(16))) char sm[36864];
  gemm_ln_body<true>(accbf, out_wb, out_b, Sseq, Z, Zbf,
                     lno_g, lno_b, 1024, blockIdx.x * 32, sm);
}

__global__ __launch_bounds__(256)
void offwgt_k(const unsigned short* Qbf, const unsigned short* owb,
              const float* bias144, float* offwgt) {
  __shared__ __attribute__((aligned(16))) unsigned short As[4096];
  __shared__ __attribute__((aligned(16))) unsigned short Bs[8192];
  gemm_body<64, 128, 2, 2, 0>(Qbf, owb, bias144, offwgt, nullptr, 144, 256, 144,
                              nullptr, nullptr, blockIdx.y * 64, blockIdx.x * 128, As, Bs);
}

__global__ __launch_bounds__(256)
void fc1_k(const unsigned short* Zbf, const unsigned short* fc1_wb,
           const float* fc1_b, unsigned short* hbf) {
  __shared__ __attribute__((aligned(16))) unsigned short As[8192];
  __shared__ __attribute__((aligned(16))) unsigned short Bs[8192];
  gemm_body<128, 128, 2, 2, 1>(Zbf, fc1_wb, fc1_b, nullptr, hbf, 1024, 256, 1024,
                               nullptr, nullptr, blockIdx.y * 128, blockIdx.x * 128, As, Bs);
}

__global__ __launch_bounds__(256)
void fc2_k(const unsigned short* hbf, const unsigned short* fc2_wb,
           const float* fc2_b, const float* Z, float* outp) {
  __shared__ __attribute__((aligned(16))) unsigned short As[4096];
  __shared__ __attribute__((aligned(16))) unsigned short Bs[4096];
  gemm_body<64, 64, 2, 2, 2>(hbf, fc2_wb, fc2_b, nullptr, nullptr, 256, 1024, 256,
                             Z, outp, blockIdx.y * 64, blockIdx.x * 64, As, Bs);
}

// ================================================================= sampling
__global__ __launch_bounds__(256)
void sample_k(const float* __restrict__ ow, const float* __restrict__ sim,
              const unsigned short* __restrict__ V0, const unsigned short* __restrict__ V1,
              const unsigned short* __restrict__ V2, unsigned short* __restrict__ acc) {
  int bn = blockIdx.x;
  int q = ((bn & 7) << 10) | (bn >> 3);   // XCD-locality swizzle
  int b = q >> 12, n = q & (NQ - 1);
  int tid = threadIdx.x, head = tid >> 6, lane = tid & 63;

  __shared__ float s_w[48];
  __shared__ int   s_xy[48][2];
  __shared__ float s_f[48][2];
  __shared__ int   s_off[192];
  __shared__ float s_twt[192];

  if (tid < 48) {
    int hh = tid / 12, pt = tid % 12, l = pt >> 2, mm = pt & 3;
    int oidx = (hh * 3 + l) * 4 + mm;
    float offx = ow[(size_t)q * 144 + oidx * 2 + 0];
    float offy = ow[(size_t)q * 144 + oidx * 2 + 1];
    float refx = ((n & 63) + 0.5f) * (1.f / 64.f);
    float refy = ((n >> 6) + 0.5f) * (1.f / 64.f);
    float gx = tanhf((refx + offx) * 2.f - 1.f);
    float gy = tanhf((refy + offy) * 2.f - 1.f);
    gx = fminf(1.f, fmaxf(-1.f, gx));
    gy = fminf(1.f, fmaxf(-1.f, gy));
    int Wl = 64 >> l;
    float x = (gx + 1.f) * 0.5f * (float)(Wl - 1);
    float y = (gy + 1.f) * 0.5f * (float)(Wl - 1);
    float x0 = floorf(x), y0 = floorf(y);
    s_xy[tid][0] = (int)x0;
    s_xy[tid][1] = (int)y0;
    s_f[tid][0] = x - x0;
    s_f[tid][1] = y - y0;
    s_w[tid] = ow[(size_t)q * 144 + 96 + oidx] * (sim[q] + 0.001f);
  }
  __syncthreads();
  if (tid < 4) {
    float mx = -1e30f;
    #pragma unroll
    for (int i = 0; i < 12; i++) mx = fmaxf(mx, s_w[tid * 12 + i]);
    float e[12], ssum = 0.f;
    #pragma unroll
    for (int i = 0; i < 12; i++) { e[i] = expf(s_w[tid * 12 + i] - mx); ssum += e[i]; }
    float inv = 1.f / ssum;
    #pragma unroll
    for (int i = 0; i < 12; i++) s_w[tid * 12 + i] = e[i] * inv;
  }
  __syncthreads();
  if (tid < 192) {
    int s = tid >> 2, tap = tid & 3;
    int l = (s % 12) >> 2;
    int Wl = 64 >> l;
    int X = s_xy[s][0] + (tap & 1), Y = s_xy[s][1] + (tap >> 1);
    bool valid = (X >= 0 && X < Wl && Y >= 0 && Y < Wl);
    float wx = (tap & 1) ? s_f[s][0] : 1.f - s_f[s][0];
    float wy = (tap >> 1) ? s_f[s][1] : 1.f - s_f[s][1];
    s_twt[tid] = valid ? s_w[s] * wx * wy : 0.f;
    int Xc = min(max(X, 0), Wl - 1), Yc = min(max(Y, 0), Wl - 1);
    s_off[tid] = (Yc * Wl + Xc) << 8;   // ushort units (256 ch/pixel)
  }
  __syncthreads();

  const unsigned short* B0 = V0 + (size_t)b * 4096 * CC;
  const unsigned short* B1 = V1 + (size_t)b * 1024 * CC;
  const unsigned short* B2 = V2 + (size_t)b * 256 * CC;
  int lane4 = lane * 4;
  float4 a = make_float4(0.f, 0.f, 0.f, 0.f);
  #pragma unroll
  for (int pt = 0; pt < 12; pt++) {
    const unsigned short* base = (pt < 4) ? B0 : (pt < 8) ? B1 : B2;
    int s = head * 12 + pt;
    #pragma unroll
    for (int tap = 0; tap < 4; tap++) {
      int off = s_off[s * 4 + tap];
      float w = s_twt[s * 4 + tap];
      const uint2 u = *(const uint2*)(base + off + lane4);
      a.x = fmaf(w, __uint_as_float(u.x << 16), a.x);
      a.y = fmaf(w, __uint_as_float(u.x & 0xffff0000u), a.y);
      a.z = fmaf(w, __uint_as_float(u.y << 16), a.z);
      a.w = fmaf(w, __uint_as_float(u.y & 0xffff0000u), a.w);
    }
  }
  ushort4 r;
  r.x = f2bf(a.x); r.y = f2bf(a.y); r.z = f2bf(a.z); r.w = f2bf(a.w);
  *(ushort4*)(acc + (size_t)q * 1024 + head * CC + lane4) = r;
}

// ================================================================= launch
extern "C" void kernel_launch(void* const* d_in, const int* in_sizes, int n_in,
                              void* d_out, int out_size, void* d_ws, size_t ws_size,
                              hipStream_t stream) {
  const float* S     = (const float*)d_in[0];
  const float* f0    = (const float*)d_in[1];
  const float* f1    = (const float*)d_in[2];
  const float* f2    = (const float*)d_in[3];
  const float* sim   = (const float*)d_in[4];
  const float* vw0   = (const float*)d_in[5];
  const float* vb0   = (const float*)d_in[6];
  const float* vw1   = (const float*)d_in[7];
  const float* vb1   = (const float*)d_in[8];
  const float* vw2   = (const float*)d_in[9];
  const float* vb2   = (const float*)d_in[10];
  const float* q_w   = (const float*)d_in[11];
  const float* q_b   = (const float*)d_in[12];
  const float* off_w = (const float*)d_in[13];
  const float* off_b = (const float*)d_in[14];
  const float* wgt_w = (const float*)d_in[15];
  const float* wgt_b = (const float*)d_in[16];
  const float* out_w = (const float*)d_in[17];
  const float* out_b = (const float*)d_in[18];
  const float* lnq_g = (const float*)d_in[19];
  const float* lnq_b = (const float*)d_in[20];
  const float* lno_g = (const float*)d_in[21];
  const float* lno_b = (const float*)d_in[22];
  const float* fc1_w = (const float*)d_in[23];
  const float* fc1_b = (const float*)d_in[24];
  const float* fc2_w = (const float*)d_in[25];
  const float* fc2_b = (const float*)d_in[26];

  char* p = (char*)d_ws;
  float* Sseq   = (float*)p; p += 8388608;               // [8192][256] fp32
  float* Z      = (float*)p; p += 8388608;               // [8192][256] fp32
  float* offwgt = (float*)p; p += 4718592;               // [8192][144]
  float* bias144 = (float*)p; p += 1024;
  unsigned short* Sbf   = (unsigned short*)p; p += 4194304;
  unsigned short* Qbf   = (unsigned short*)p; p += 4194304;   // alias Zbf
  unsigned short* accbf = (unsigned short*)p; p += 16777216;  // alias Xf*, hbf
  unsigned short* V0b   = (unsigned short*)p; p += 4194304;
  unsigned short* V1b   = (unsigned short*)p; p += 1048576;
  unsigned short* V2b   = (unsigned short*)p; p += 262144;
  unsigned short* q_wb   = (unsigned short*)p; p += 131072;
  unsigned short* owb    = (unsigned short*)p; p += 131072;
  unsigned short* vw0b   = (unsigned short*)p; p += 131072;
  unsigned short* vw1b   = (unsigned short*)p; p += 262144;
  unsigned short* vw2b   = (unsigned short*)p; p += 524288;
  unsigned short* out_wb = (unsigned short*)p; p += 524288;
  unsigned short* fc1_wb = (unsigned short*)p; p += 524288;
  unsigned short* fc2_wb = (unsigned short*)p; p += 524288;

  unsigned short* Xf0 = accbf;
  unsigned short* Xf1 = accbf + 2097152;
  unsigned short* Xf2 = accbf + 3145728;
  unsigned short* Zbf = Qbf;
  unsigned short* hbf = accbf;
  float* outp = (float*)d_out;

  prep_all_k<<<2944, 256, 0, stream>>>(S, f0, f1, f2, q_w, off_w, wgt_w,
      vw0, vw1, vw2, out_w, fc1_w, fc2_w, off_b, wgt_b,
      Sseq, Sbf, Xf0, Xf1, Xf2, q_wb, owb, vw0b, vw1b, vw2b, out_wb,
      fc1_wb, fc2_wb, bias144);

  qv_k<<<592, 256, 0, stream>>>(Sbf, q_wb, q_b, lnq_g, lnq_b, Qbf,
      Xf0, Xf1, Xf2, vw0b, vw1b, vw2b, vb0, vb1, vb2, V0b, V1b, V2b);

  offwgt_k<<<dim3(2, 128), 256, 0, stream>>>(Qbf, owb, bias144, offwgt);

  sample_k<<<8192, 256, 0, stream>>>(offwgt, sim, V0b, V1b, V2b, accbf);

  outln_k<<<256, 256, 0, stream>>>(accbf, out_wb, out_b, Sseq, Z, Zbf,
      lno_g, lno_b);

  fc1_k<<<dim3(8, 64), 256, 0, stream>>>(Zbf, fc1_wb, fc1_b, hbf);

  fc2_k<<<dim3(4, 128), 256, 0, stream>>>(hbf, fc2_wb, fc2_b, Z, outp);
}

// Round 5
// 276.343 us; speedup vs baseline: 3.3448x; 1.0714x over previous
//
#include <hip/hip_runtime.h>
#include <hip/hip_bf16.h>
#include <math.h>

#define NQ 4096
#define CC 256

typedef __attribute__((ext_vector_type(8))) short bfrag;
typedef __attribute__((ext_vector_type(4))) float ffrag;

__device__ inline unsigned short f2bf(float x) {
  __hip_bfloat16 h = __float2bfloat16(x);
  return *reinterpret_cast<unsigned short*>(&h);
}

__device__ inline void gload16(const void* g, void* l) {
  __builtin_amdgcn_global_load_lds(
      (const __attribute__((address_space(1))) void*)g,
      (__attribute__((address_space(3))) void*)l, 16, 0, 0);
}

// ================================================================= prep mega
// 64x64 float4 transpose tile. t[64][73] fp32
__device__ void tr64(const float* __restrict__ src,
                     unsigned short* __restrict__ dstb, int Cin, int P,
                     int p0, int c0, int b, float (*t)[73]) {
  int tid = threadIdx.x;
  int rx = tid & 15, ry = tid >> 4;
  const float* Sb = src + (size_t)b * Cin * P + p0 + rx * 4;
  #pragma unroll
  for (int i = 0; i < 4; i++) {
    int r = ry + i * 16;
    float4 v = *(const float4*)(Sb + (size_t)(c0 + r) * P);
    t[r][rx * 4 + 0] = v.x; t[r][rx * 4 + 1] = v.y;
    t[r][rx * 4 + 2] = v.z; t[r][rx * 4 + 3] = v.w;
  }
  __syncthreads();
  size_t ob = (size_t)b * P * Cin;
  #pragma unroll
  for (int i = 0; i < 4; i++) {
    int pr = ry + i * 16;
    float x0 = t[rx * 4 + 0][pr], x1 = t[rx * 4 + 1][pr];
    float x2 = t[rx * 4 + 2][pr], x3 = t[rx * 4 + 3][pr];
    size_t idx = ob + (size_t)(p0 + pr) * Cin + c0 + rx * 4;
    ushort4 u4;
    u4.x = f2bf(x0); u4.y = f2bf(x1); u4.z = f2bf(x2); u4.w = f2bf(x3);
    *(ushort4*)(dstb + idx) = u4;
  }
}

// blocks: [0,512) S  [512,1024) f0  [1024,1280) f1  [1280,1408) f2
//         [1408,2688) weight float4 casts  [2688,2944) off/wgt + bias144
__global__ __launch_bounds__(256)
void prep_all_k(const float* S, const float* f0, const float* f1, const float* f2,
                const float* q_w, const float* off_w, const float* wgt_w,
                const float* vw0, const float* vw1, const float* vw2,
                const float* out_w, const float* fc1_w, const float* fc2_w,
                const float* off_b, const float* wgt_b,
                unsigned short* Sbf,
                unsigned short* Xf0, unsigned short* Xf1, unsigned short* Xf2,
                unsigned short* q_wb, unsigned short* owb,
                unsigned short* vw0b, unsigned short* vw1b, unsigned short* vw2b,
                unsigned short* out_wb, unsigned short* fc1_wb,
                unsigned short* fc2_wb, float* bias144) {
  __shared__ float t[64][73];
  int bid = blockIdx.x;
  if (bid < 512) {
    int l = bid;
    tr64(S, Sbf, 256, 4096, (l & 63) * 64, ((l >> 6) & 3) * 64, l >> 8, t);
  } else if (bid < 1024) {
    int l = bid - 512;
    tr64(f0, Xf0, 256, 4096, (l & 63) * 64, ((l >> 6) & 3) * 64, l >> 8, t);
  } else if (bid < 1280) {
    int l = bid - 1024;
    tr64(f1, Xf1, 512, 1024, (l & 15) * 64, ((l >> 4) & 7) * 64, l >> 7, t);
  } else if (bid < 1408) {
    int l = bid - 1280;
    tr64(f2, Xf2, 1024, 256, (l & 3) * 64, ((l >> 2) & 15) * 64, l >> 6, t);
  } else if (bid < 2688) {
    int i4 = (bid - 1408) * 256 + threadIdx.x;
    const float* src; unsigned short* dst;
    if (i4 < 16384)       { src = q_w;   dst = q_wb; }
    else if (i4 < 32768)  { i4 -= 16384;  src = vw0;   dst = vw0b; }
    else if (i4 < 65536)  { i4 -= 32768;  src = vw1;   dst = vw1b; }
    else if (i4 < 131072) { i4 -= 65536;  src = vw2;   dst = vw2b; }
    else if (i4 < 196608) { i4 -= 131072; src = out_w; dst = out_wb; }
    else if (i4 < 262144) { i4 -= 196608; src = fc1_w; dst = fc1_wb; }
    else                  { i4 -= 262144; src = fc2_w; dst = fc2_wb; }
    float4 v = ((const float4*)src)[i4];
    ushort4 u; u.x = f2bf(v.x); u.y = f2bf(v.y); u.z = f2bf(v.z); u.w = f2bf(v.w);
    ((ushort4*)dst)[i4] = u;
  } else {
    int e = (bid - 2688) * 256 + threadIdx.x;
    float v = (e < 24576) ? off_w[e] : (e < 36864 ? wgt_w[e - 24576] : 0.f);
    owb[e] = f2bf(v);
    if (e < 96) bias144[e] = off_b[e];
    else if (e < 144) bias144[e] = wgt_b[e - 96];
  }
}

// ================================================================= GEMM body
// BK=64, k-major LDS slots of 8 ushorts: slot = kc*R + r.
template<int BM, int BN, int WM, int WN, int EPI>
__device__ __forceinline__ void gemm_body(
    const unsigned short* __restrict__ A, const unsigned short* __restrict__ B,
    const float* __restrict__ bias, float* __restrict__ outf,
    unsigned short* __restrict__ outb, int N, int K, int ldo,
    const float* __restrict__ Zres, float* __restrict__ outT,
    int m0, int n0, unsigned short* As, unsigned short* Bs) {
  constexpr int MI = BM / (WM * 16), NI = BN / (WN * 16);
  constexpr int TA = BM / 8, TB = BN / 8;
  constexpr int LBM = (BM == 32) ? 5 : (BM == 64) ? 6 : 7;
  constexpr int LBN = (BN == 64) ? 6 : (BN == 128) ? 7 : 8;
  int tid = threadIdx.x, wave = tid >> 6, lane = tid & 63;
  int quad = lane >> 4, l16 = lane & 15;
  int wm = wave / WN, wn = wave % WN;
  const int mbase = wm * (BM / WM), nbase = wn * (BN / WN);

  ffrag acc[MI][NI];
  #pragma unroll
  for (int i = 0; i < MI; i++)
    #pragma unroll
    for (int j = 0; j < NI; j++) acc[i][j] = (ffrag)0.f;

  for (int k0 = 0; k0 < K; k0 += 64) {
    __syncthreads();
    for (int t = wave; t < TA + TB; t += 4) {
      if (t < TA) {
        int s = t * 64 + lane;
        int kc = s >> LBM, r = s & (BM - 1);
        gload16(A + (size_t)(m0 + r) * K + k0 + kc * 8, (char*)As + t * 1024);
      } else {
        int s = (t - TA) * 64 + lane;
        int kc = s >> LBN, r = s & (BN - 1);
        gload16(B + (size_t)(n0 + r) * K + k0 + kc * 8, (char*)Bs + (t - TA) * 1024);
      }
    }
    __syncthreads();
    #pragma unroll
    for (int ks = 0; ks < 2; ks++) {
      bfrag af[MI], bf[NI];
      #pragma unroll
      for (int mi = 0; mi < MI; mi++)
        af[mi] = *(const bfrag*)(As + ((((ks * 4 + quad) << LBM) + mbase + mi * 16 + l16) << 3));
      #pragma unroll
      for (int ni = 0; ni < NI; ni++)
        bf[ni] = *(const bfrag*)(Bs + ((((ks * 4 + quad) << LBN) + nbase + ni * 16 + l16) << 3));
      #pragma unroll
      for (int mi = 0; mi < MI; mi++)
        #pragma unroll
        for (int ni = 0; ni < NI; ni++)
          acc[mi][ni] = __builtin_amdgcn_mfma_f32_16x16x32_bf16(
              af[mi], bf[ni], acc[mi][ni], 0, 0, 0);
    }
  }

  if (EPI == 2) {  // + bias + Zres, transposed float4 store along m
    #pragma unroll
    for (int mi = 0; mi < MI; mi++) {
      int mrow = m0 + mbase + mi * 16 + quad * 4;
      int bb = mrow >> 12, q0 = mrow & (NQ - 1);
      #pragma unroll
      for (int ni = 0; ni < NI; ni++) {
        int n = n0 + nbase + ni * 16 + l16;
        float bv = bias[n];
        float4 v;
        v.x = acc[mi][ni][0] + bv + Zres[(size_t)(mrow + 0) * CC + n];
        v.y = acc[mi][ni][1] + bv + Zres[(size_t)(mrow + 1) * CC + n];
        v.z = acc[mi][ni][2] + bv + Zres[(size_t)(mrow + 2) * CC + n];
        v.w = acc[mi][ni][3] + bv + Zres[(size_t)(mrow + 3) * CC + n];
        *(float4*)(outT + ((size_t)(bb * CC + n)) * NQ + q0) = v;
      }
    }
  } else {
    #pragma unroll
    for (int mi = 0; mi < MI; mi++) {
      int mrow = m0 + mbase + mi * 16 + quad * 4;
      #pragma unroll
      for (int ni = 0; ni < NI; ni++) {
        int n = n0 + nbase + ni * 16 + l16;
        if (n < N) {
          float bv = bias[n];
          #pragma unroll
          for (int r = 0; r < 4; r++) {
            float v = acc[mi][ni][r] + bv;
            if (EPI == 1) {
              v = 0.5f * v * (1.f + erff(v * 0.70710678118654752f));
              outb[(size_t)(mrow + r) * ldo + n] = f2bf(v);
            } else if (EPI == 3) {
              outb[(size_t)(mrow + r) * ldo + n] = f2bf(v);
            } else {
              outf[(size_t)(mrow + r) * ldo + n] = v;
            }
          }
        }
      }
    }
  }
}

// ================================================================= GEMM + LN
// BM=32, BN=256(full), BK=64. Residual read directly from S [B][C][NQ].
template<bool RES>
__device__ __forceinline__ void gemm_ln_body(
    const unsigned short* __restrict__ A, const unsigned short* __restrict__ B,
    const float* __restrict__ bias, const float* __restrict__ Sraw,
    float* __restrict__ outf, unsigned short* __restrict__ outb,
    const float* __restrict__ g, const float* __restrict__ be,
    int K, int m0, char* sm) {
  unsigned short* As = (unsigned short*)sm;
  unsigned short* Bs = (unsigned short*)(sm + 4096);
  float* L = (float*)sm;

  int tid = threadIdx.x, wave = tid >> 6, lane = tid & 63;
  int quad = lane >> 4, l16 = lane & 15;

  ffrag acc[2][4];
  #pragma unroll
  for (int i = 0; i < 2; i++)
    #pragma unroll
    for (int j = 0; j < 4; j++) acc[i][j] = (ffrag)0.f;

  for (int k0 = 0; k0 < K; k0 += 64) {
    __syncthreads();
    for (int t = wave; t < 36; t += 4) {
      if (t < 4) {
        int s = t * 64 + lane;
        int kc = s >> 5, r = s & 31;
        gload16(A + (size_t)(m0 + r) * K + k0 + kc * 8, sm + t * 1024);
      } else {
        int s = (t - 4) * 64 + lane;
        int kc = s >> 8, r = s & 255;
        gload16(B + (size_t)r * K + k0 + kc * 8, sm + 4096 + (t - 4) * 1024);
      }
    }
    __syncthreads();
    #pragma unroll
    for (int ks = 0; ks < 2; ks++) {
      bfrag af[2], bf[4];
      #pragma unroll
      for (int mi = 0; mi < 2; mi++)
        af[mi] = *(const bfrag*)(As + ((((ks * 4 + quad) << 5) + mi * 16 + l16) << 3));
      #pragma unroll
      for (int ni = 0; ni < 4; ni++)
        bf[ni] = *(const bfrag*)(Bs + ((((ks * 4 + quad) << 8) + wave * 64 + ni * 16 + l16) << 3));
      #pragma unroll
      for (int mi = 0; mi < 2; mi++)
        #pragma unroll
        for (int ni = 0; ni < 4; ni++)
          acc[mi][ni] = __builtin_amdgcn_mfma_f32_16x16x32_bf16(
              af[mi], bf[ni], acc[mi][ni], 0, 0, 0);
    }
  }
  __syncthreads();

  #pragma unroll
  for (int mi = 0; mi < 2; mi++) {
    int row = mi * 16 + quad * 4;
    int m = m0 + row;
    int bb = m >> 12, q0 = m & (NQ - 1);
    #pragma unroll
    for (int ni = 0; ni < 4; ni++) {
      int col = wave * 64 + ni * 16 + l16;
      float bv = bias[col];
      float4 s4 = make_float4(0.f, 0.f, 0.f, 0.f);
      if (RES) s4 = *(const float4*)(Sraw + ((size_t)(bb * CC + col)) * NQ + q0);
      L[(row + 0) * 264 + col] = acc[mi][ni][0] + bv + s4.x;
      L[(row + 1) * 264 + col] = acc[mi][ni][1] + bv + s4.y;
      L[(row + 2) * 264 + col] = acc[mi][ni][2] + bv + s4.z;
      L[(row + 3) * 264 + col] = acc[mi][ni][3] + bv + s4.w;
    }
  }
  __syncthreads();

  int row = tid >> 3, j = tid & 7;
  int seg = ((j + row) & 7) * 32;
  const float* Lr = L + row * 264 + seg;
  float s1 = 0.f, s2 = 0.f;
  #pragma unroll
  for (int i = 0; i < 8; i++) {
    float4 t4 = *(const float4*)(Lr + i * 4);
    s1 += t4.x + t4.y + t4.z + t4.w;
    s2 += t4.x * t4.x + t4.y * t4.y + t4.z * t4.z + t4.w * t4.w;
  }
  #pragma unroll
  for (int o = 1; o < 8; o <<= 1) {
    s1 += __shfl_xor(s1, o);
    s2 += __shfl_xor(s2, o);
  }
  float mu = s1 * (1.f / 256.f);
  float var = s2 * (1.f / 256.f) - mu * mu;
  float rs = rsqrtf(var + 1e-5f);
  int gm = m0 + row;
  #pragma unroll
  for (int i = 0; i < 8; i++) {
    int col = seg + i * 4;
    float4 t4 = *(const float4*)(Lr + i * 4);
    float4 gg = *(const float4*)(g + col);
    float4 bb4 = *(const float4*)(be + col);
    float4 y;
    y.x = (t4.x - mu) * rs * gg.x + bb4.x;
    y.y = (t4.y - mu) * rs * gg.y + bb4.y;
    y.z = (t4.z - mu) * rs * gg.z + bb4.z;
    y.w = (t4.w - mu) * rs * gg.w + bb4.w;
    ushort4 ub;
    ub.x = f2bf(y.x); ub.y = f2bf(y.y); ub.z = f2bf(y.z); ub.w = f2bf(y.w);
    *(ushort4*)(outb + (size_t)gm * CC + col) = ub;
    if (RES) *(float4*)(outf + (size_t)gm * CC + col) = y;
  }
}

// ================================================================= kernels
__global__ __launch_bounds__(256)
void qv_k(const unsigned short* Sbf, const unsigned short* q_wb, const float* q_b,
          const float* lnq_g, const float* lnq_b, unsigned short* Qbf,
          const unsigned short* Xf0, const unsigned short* Xf1,
          const unsigned short* Xf2, const unsigned short* vw0b,
          const unsigned short* vw1b, const unsigned short* vw2b,
          const float* vb0, const float* vb1, const float* vb2,
          unsigned short* V0b, unsigned short* V1b, unsigned short* V2b) {
  __shared__ __attribute__((aligned(16))) char sm[36864];
  int bid = blockIdx.x;
  if (bid < 256) {
    gemm_ln_body<false>(Sbf, q_wb, q_b, nullptr, nullptr, Qbf,
                        lnq_g, lnq_b, 256, bid * 32, sm);
  } else {
    int lb = bid - 256;
    const unsigned short *A, *B; const float* bias; unsigned short* out; int K;
    if (lb < 256)      { A = Xf0; B = vw0b; bias = vb0; out = V0b; K = 256; }
    else if (lb < 320) { A = Xf1; B = vw1b; bias = vb1; out = V1b; K = 512;  lb -= 256; }
    else               { A = Xf2; B = vw2b; bias = vb2; out = V2b; K = 1024; lb -= 320; }
    int n0 = (lb & 1) * 128, m0 = (lb >> 1) * 64;
    gemm_body<64, 128, 2, 2, 3>(A, B, bias, nullptr, out, 256, K, 256,
                                nullptr, nullptr, m0, n0,
                                (unsigned short*)sm, (unsigned short*)(sm + 8192));
  }
}

__global__ __launch_bounds__(256)
void outln_k(const unsigned short* accbf, const unsigned short* out_wb,
             const float* out_b, const float* S, float* Z,
             unsigned short* Zbf, const float* lno_g, const float* lno_b) {
  __shared__ __attribute__((aligned(16))) char sm[36864];
  gemm_ln_body<true>(accbf, out_wb, out_b, S, Z, Zbf,
                     lno_g, lno_b, 1024, blockIdx.x * 32, sm);
}

__global__ __launch_bounds__(256)
void offwgt_k(const unsigned short* Qbf, const unsigned short* owb,
              const float* bias144, float* offwgt) {
  __shared__ __attribute__((aligned(16))) unsigned short As[4096];
  __shared__ __attribute__((aligned(16))) unsigned short Bs[8192];
  gemm_body<64, 128, 2, 2, 0>(Qbf, owb, bias144, offwgt, nullptr, 144, 256, 144,
                              nullptr, nullptr, blockIdx.y * 64, blockIdx.x * 128, As, Bs);
}

__global__ __launch_bounds__(256)
void fc1_k(const unsigned short* Zbf, const unsigned short* fc1_wb,
           const float* fc1_b, unsigned short* hbf) {
  __shared__ __attribute__((aligned(16))) unsigned short As[8192];
  __shared__ __attribute__((aligned(16))) unsigned short Bs[8192];
  gemm_body<128, 128, 2, 2, 1>(Zbf, fc1_wb, fc1_b, nullptr, hbf, 1024, 256, 1024,
                               nullptr, nullptr, blockIdx.y * 128, blockIdx.x * 128, As, Bs);
}

__global__ __launch_bounds__(256)
void fc2_k(const unsigned short* hbf, const unsigned short* fc2_wb,
           const float* fc2_b, const float* Z, float* outp) {
  __shared__ __attribute__((aligned(16))) unsigned short As[4096];
  __shared__ __attribute__((aligned(16))) unsigned short Bs[4096];
  gemm_body<64, 64, 2, 2, 2>(hbf, fc2_wb, fc2_b, nullptr, nullptr, 256, 1024, 256,
                             Z, outp, blockIdx.y * 64, blockIdx.x * 64, As, Bs);
}

// ================================================================= sampling
// dual-tap: lanes 0-31 take tap 2i, lanes 32-63 tap 2i+1; each lane 8 ch (uint4)
__global__ __launch_bounds__(256)
void sample_k(const float* __restrict__ ow, const float* __restrict__ sim,
              const unsigned short* __restrict__ V0, const unsigned short* __restrict__ V1,
              const unsigned short* __restrict__ V2, unsigned short* __restrict__ acc) {
  int bn = blockIdx.x;
  int q = ((bn & 7) << 10) | (bn >> 3);   // XCD-locality swizzle
  int b = q >> 12, n = q & (NQ - 1);
  int tid = threadIdx.x, head = tid >> 6, lane = tid & 63;
  int half = lane >> 5, l32 = lane & 31;

  __shared__ float s_w[48];
  __shared__ int   s_xy[48][2];
  __shared__ float s_f[48][2];
  __shared__ uint2 s_ow[192];   // .x = offset (ushort units), .y = weight bits

  if (tid < 48) {
    int hh = tid / 12, pt = tid % 12, l = pt >> 2, mm = pt & 3;
    int oidx = (hh * 3 + l) * 4 + mm;
    float offx = ow[(size_t)q * 144 + oidx * 2 + 0];
    float offy = ow[(size_t)q * 144 + oidx * 2 + 1];
    float refx = ((n & 63) + 0.5f) * (1.f / 64.f);
    float refy = ((n >> 6) + 0.5f) * (1.f / 64.f);
    float gx = tanhf((refx + offx) * 2.f - 1.f);
    float gy = tanhf((refy + offy) * 2.f - 1.f);
    gx = fminf(1.f, fmaxf(-1.f, gx));
    gy = fminf(1.f, fmaxf(-1.f, gy));
    int Wl = 64 >> l;
    float x = (gx + 1.f) * 0.5f * (float)(Wl - 1);
    float y = (gy + 1.f) * 0.5f * (float)(Wl - 1);
    float x0 = floorf(x), y0 = floorf(y);
    s_xy[tid][0] = (int)x0;
    s_xy[tid][1] = (int)y0;
    s_f[tid][0] = x - x0;
    s_f[tid][1] = y - y0;
    s_w[tid] = ow[(size_t)q * 144 + 96 + oidx] * (sim[q] + 0.001f);
  }
  __syncthreads();
  if (tid < 4) {
    float mx = -1e30f;
    #pragma unroll
    for (int i = 0; i < 12; i++) mx = fmaxf(mx, s_w[tid * 12 + i]);
    float e[12], ssum = 0.f;
    #pragma unroll
    for (int i = 0; i < 12; i++) { e[i] = expf(s_w[tid * 12 + i] - mx); ssum += e[i]; }
    float inv = 1.f / ssum;
    #pragma unroll
    for (int i = 0; i < 12; i++) s_w[tid * 12 + i] = e[i] * inv;
  }
  __syncthreads();
  if (tid < 192) {
    int s = tid >> 2, tap = tid & 3;
    int l = (s % 12) >> 2;
    int Wl = 64 >> l;
    int X = s_xy[s][0] + (tap & 1), Y = s_xy[s][1] + (tap >> 1);
    bool valid = (X >= 0 && X < Wl && Y >= 0 && Y < Wl);
    float wx = (tap & 1) ? s_f[s][0] : 1.f - s_f[s][0];
    float wy = (tap >> 1) ? s_f[s][1] : 1.f - s_f[s][1];
    float twt = valid ? s_w[s] * wx * wy : 0.f;
    int Xc = min(max(X, 0), Wl - 1), Yc = min(max(Y, 0), Wl - 1);
    s_ow[tid].x = (unsigned)((Yc * Wl + Xc) << 8);   // ushort units
    s_ow[tid].y = __float_as_uint(twt);
  }
  __syncthreads();

  const unsigned short* B0 = V0 + (size_t)b * 4096 * CC;
  const unsigned short* B1 = V1 + (size_t)b * 1024 * CC;
  const unsigned short* B2 = V2 + (size_t)b * 256 * CC;
  int ch8 = l32 * 8;
  float a0 = 0.f, a1 = 0.f, a2 = 0.f, a3 = 0.f;
  float a4 = 0.f, a5 = 0.f, a6 = 0.f, a7 = 0.f;
  #pragma unroll
  for (int it = 0; it < 24; it++) {
    // flat tap = it*2 + half in [0,48); level = flat>>4 -> it<8:L0, it<16:L1 else L2
    const unsigned short* base = (it < 8) ? B0 : (it < 16) ? B1 : B2;
    uint2 owv = s_ow[head * 48 + it * 2 + half];
    float w = __uint_as_float(owv.y);
    const uint4 u = *(const uint4*)(base + owv.x + ch8);
    a0 = fmaf(w, __uint_as_float(u.x << 16), a0);
    a1 = fmaf(w, __uint_as_float(u.x & 0xffff0000u), a1);
    a2 = fmaf(w, __uint_as_float(u.y << 16), a2);
    a3 = fmaf(w, __uint_as_float(u.y & 0xffff0000u), a3);
    a4 = fmaf(w, __uint_as_float(u.z << 16), a4);
    a5 = fmaf(w, __uint_as_float(u.z & 0xffff0000u), a5);
    a6 = fmaf(w, __uint_as_float(u.w << 16), a6);
    a7 = fmaf(w, __uint_as_float(u.w & 0xffff0000u), a7);
  }
  // cross-half reduce (even taps in lanes 0-31, odd taps in 32-63)
  a0 += __shfl_xor(a0, 32); a1 += __shfl_xor(a1, 32);
  a2 += __shfl_xor(a2, 32); a3 += __shfl_xor(a3, 32);
  a4 += __shfl_xor(a4, 32); a5 += __shfl_xor(a5, 32);
  a6 += __shfl_xor(a6, 32); a7 += __shfl_xor(a7, 32);
  if (half == 0) {
    uint4 r;
    r.x = (unsigned)f2bf(a0) | ((unsigned)f2bf(a1) << 16);
    r.y = (unsigned)f2bf(a2) | ((unsigned)f2bf(a3) << 16);
    r.z = (unsigned)f2bf(a4) | ((unsigned)f2bf(a5) << 16);
    r.w = (unsigned)f2bf(a6) | ((unsigned)f2bf(a7) << 16);
    *(uint4*)(acc + (size_t)q * 1024 + head * CC + ch8) = r;
  }
}

// ================================================================= launch
extern "C" void kernel_launch(void* const* d_in, const int* in_sizes, int n_in,
                              void* d_out, int out_size, void* d_ws, size_t ws_size,
                              hipStream_t stream) {
  const float* S     = (const float*)d_in[0];
  const float* f0    = (const float*)d_in[1];
  const float* f1    = (const float*)d_in[2];
  const float* f2    = (const float*)d_in[3];
  const float* sim   = (const float*)d_in[4];
  const float* vw0   = (const float*)d_in[5];
  const float* vb0   = (const float*)d_in[6];
  const float* vw1   = (const float*)d_in[7];
  const float* vb1   = (const float*)d_in[8];
  const float* vw2   = (const float*)d_in[9];
  const float* vb2   = (const float*)d_in[10];
  const float* q_w   = (const float*)d_in[11];
  const float* q_b   = (const float*)d_in[12];
  const float* off_w = (const float*)d_in[13];
  const float* off_b = (const float*)d_in[14];
  const float* wgt_w = (const float*)d_in[15];
  const float* wgt_b = (const float*)d_in[16];
  const float* out_w = (const float*)d_in[17];
  const float* out_b = (const float*)d_in[18];
  const float* lnq_g = (const float*)d_in[19];
  const float* lnq_b = (const float*)d_in[20];
  const float* lno_g = (const float*)d_in[21];
  const float* lno_b = (const float*)d_in[22];
  const float* fc1_w = (const float*)d_in[23];
  const float* fc1_b = (const float*)d_in[24];
  const float* fc2_w = (const float*)d_in[25];
  const float* fc2_b = (const float*)d_in[26];

  char* p = (char*)d_ws;
  float* Z      = (float*)p; p += 8388608;               // [8192][256] fp32
  float* offwgt = (float*)p; p += 4718592;               // [8192][144]
  float* bias144 = (float*)p; p += 1024;
  unsigned short* Sbf   = (unsigned short*)p; p += 4194304;
  unsigned short* Qbf   = (unsigned short*)p; p += 4194304;   // alias Zbf
  unsigned short* accbf = (unsigned short*)p; p += 16777216;  // alias Xf*, hbf
  unsigned short* V0b   = (unsigned short*)p; p += 4194304;
  unsigned short* V1b   = (unsigned short*)p; p += 1048576;
  unsigned short* V2b   = (unsigned short*)p; p += 262144;
  unsigned short* q_wb   = (unsigned short*)p; p += 131072;
  unsigned short* owb    = (unsigned short*)p; p += 131072;
  unsigned short* vw0b   = (unsigned short*)p; p += 131072;
  unsigned short* vw1b   = (unsigned short*)p; p += 262144;
  unsigned short* vw2b   = (unsigned short*)p; p += 524288;
  unsigned short* out_wb = (unsigned short*)p; p += 524288;
  unsigned short* fc1_wb = (unsigned short*)p; p += 524288;
  unsigned short* fc2_wb = (unsigned short*)p; p += 524288;

  unsigned short* Xf0 = accbf;
  unsigned short* Xf1 = accbf + 2097152;
  unsigned short* Xf2 = accbf + 3145728;
  unsigned short* Zbf = Qbf;
  unsigned short* hbf = accbf;
  float* outp = (float*)d_out;

  prep_all_k<<<2944, 256, 0, stream>>>(S, f0, f1, f2, q_w, off_w, wgt_w,
      vw0, vw1, vw2, out_w, fc1_w, fc2_w, off_b, wgt_b,
      Sbf, Xf0, Xf1, Xf2, q_wb, owb, vw0b, vw1b, vw2b, out_wb,
      fc1_wb, fc2_wb, bias144);

  qv_k<<<592, 256, 0, stream>>>(Sbf, q_wb, q_b, lnq_g, lnq_b, Qbf,
      Xf0, Xf1, Xf2, vw0b, vw1b, vw2b, vb0, vb1, vb2, V0b, V1b, V2b);

  offwgt_k<<<dim3(2, 128), 256, 0, stream>>>(Qbf, owb, bias144, offwgt);

  sample_k<<<8192, 256, 0, stream>>>(offwgt, sim, V0b, V1b, V2b, accbf);

  outln_k<<<256, 256, 0, stream>>>(accbf, out_wb, out_b, S, Z, Zbf,
      lno_g, lno_b);

  fc1_k<<<dim3(8, 64), 256, 0, stream>>>(Zbf, fc1_wb, fc1_b, hbf);

  fc2_k<<<dim3(4, 128), 256, 0, stream>>>(hbf, fc2_wb, fc2_b, Z, outp);
}